// Round 1
// baseline (528.805 us; speedup 1.0000x reference)
//
#include <hip/hip_runtime.h>
#include <float.h>

// Problem constants
#define B_  2
#define ST_ 8      // teacher frames
#define SS_ 4      // student frames
#define P_  1369
#define D_  1024
#define R_  128
#define NS_ 128
#define K_  4
#define M_  5476   // 4 * P_ (extra frames 1,3,5,7 flattened)

// Workspace layout (float offsets). Total ~1.95M floats (~7.8 MB).
#define OFF_INVN  0u
#define OFF_REFT  11008u
#define OFF_REFS  (OFF_REFT + (unsigned)(B_*R_*D_))
#define OFF_PRRT  (OFF_REFS + (unsigned)(B_*R_*D_))
#define OFF_PRRS  (OFF_PRRT + 256u)
#define OFF_C     (OFF_PRRS + 256u)
#define OFF_IDX   (OFF_C + (unsigned)(B_*R_*M_))
#define OFF_PRST  (OFF_IDX + 1024u)
#define OFF_PRSS  (OFF_PRST + 1024u)
#define OFF_PSS   (OFF_PRSS + 1024u)
#define OFF_IB1T  (OFF_PSS + 1024u)
#define OFF_IB1S  (OFF_IB1T + 1024u)

__device__ __forceinline__ float dot4(const float4 a, const float4 b) {
  return a.x*b.x + a.y*b.y + a.z*b.z + a.w*b.w;
}

// ---------------------------------------------------------------------------
// K1: inverse norms of the 4 "extra" teacher frames' rows. One wave per row.
__global__ __launch_bounds__(256) void k_extra_norms(const float* __restrict__ teacher,
                                                     float* __restrict__ invn) {
  int row = blockIdx.x * 4 + (threadIdx.x >> 6);
  int lane = threadIdx.x & 63;
  if (row >= B_ * M_) return;
  int b = row / M_, m = row % M_;
  int j = m / P_, p = m % P_;                 // extra frame j -> teacher frame 1+2j
  const float* src = teacher + (((size_t)b * ST_ + 1 + 2 * j) * P_ + p) * D_;
  float s = 0.f;
  #pragma unroll
  for (int it = 0; it < 4; ++it) {
    float4 v = *(const float4*)(src + (it * 64 + lane) * 4);
    s += dot4(v, v);
  }
  for (int o = 32; o; o >>= 1) s += __shfl_down(s, o);
  if (lane == 0) invn[row] = 1.f / fmaxf(sqrtf(s), 1e-12f);
}

// ---------------------------------------------------------------------------
// K1b: gather ref_t / ref_s rows (frame 0, ref_perm) and their squared norms.
__global__ __launch_bounds__(256) void k_ref_gather(const float* __restrict__ teacher,
                                                    const float* __restrict__ student,
                                                    const int* __restrict__ ref_perm,
                                                    float* __restrict__ reft,
                                                    float* __restrict__ refs,
                                                    float* __restrict__ prrt,
                                                    float* __restrict__ prrs) {
  int br = blockIdx.x;          // b*R + r
  int b = br / R_, r = br % R_;
  int p = ref_perm[r];
  const float* st = teacher + (((size_t)b * ST_ + 0) * P_ + p) * D_;
  const float* ss = student + (((size_t)b * SS_ + 0) * P_ + p) * D_;
  float* dt = reft + (size_t)br * D_;
  float* dsp = refs + (size_t)br * D_;
  int t = threadIdx.x;
  float4 vt = *(const float4*)(st + t * 4);
  float4 vs = *(const float4*)(ss + t * 4);
  *(float4*)(dt + t * 4) = vt;
  *(float4*)(dsp + t * 4) = vs;
  float at = dot4(vt, vt);
  float as = dot4(vs, vs);
  for (int o = 32; o; o >>= 1) { at += __shfl_down(at, o); as += __shfl_down(as, o); }
  __shared__ float red[16];
  int w = t >> 6, lane = t & 63;
  if (lane == 0) { red[w] = at; red[8 + w] = as; }
  __syncthreads();
  if (t == 0) {
    prrt[br] = red[0] + red[1] + red[2] + red[3];
    prrs[br] = red[8] + red[9] + red[10] + red[11];
  }
}

// ---------------------------------------------------------------------------
// K2: C[b][r][m] = (ref_t[b,r] . extra[b,m]) * invn[b,m]
// 64x64 output tile per block, K-chunks of 32 staged transposed ([k][r]) in LDS.
__global__ __launch_bounds__(256) void k_sim_gemm(const float* __restrict__ teacher,
                                                  const float* __restrict__ reft,
                                                  const float* __restrict__ invn,
                                                  float* __restrict__ C) {
  const int bid = blockIdx.x;            // 2 * 2 * 86 = 344 blocks
  const int b   = bid / 172;
  const int rem = bid % 172;
  const int rt  = rem / 86;
  const int mt  = rem % 86;
  const int r0 = rt * 64, m0 = mt * 64;
  __shared__ __align__(16) float Al[32 * 68];   // [kk][r], stride 68
  __shared__ __align__(16) float El[32 * 68];
  const int t = threadIdx.x;
  const int tx = t & 15, ty = t >> 4;
  const int lr = t >> 3;                 // 0..31
  const int lk = (t & 7) * 4;            // 0,4,...,28
  const float* arow0 = reft + (size_t)(b * R_ + r0 + lr) * D_;
  const float* arow1 = reft + (size_t)(b * R_ + r0 + 32 + lr) * D_;
  const float* erow0; const float* erow1; bool ev0, ev1;
  {
    int m = m0 + lr; ev0 = m < M_;
    int mm = ev0 ? m : 0; int j = mm / P_, p = mm % P_;
    erow0 = teacher + (((size_t)b * ST_ + 1 + 2 * j) * P_ + p) * D_;
    m = m0 + 32 + lr; ev1 = m < M_;
    mm = ev1 ? m : 0; j = mm / P_; p = mm % P_;
    erow1 = teacher + (((size_t)b * ST_ + 1 + 2 * j) * P_ + p) * D_;
  }
  float acc[4][4];
  #pragma unroll
  for (int i = 0; i < 4; ++i)
    #pragma unroll
    for (int j = 0; j < 4; ++j) acc[i][j] = 0.f;

  for (int kc = 0; kc < D_; kc += 32) {
    __syncthreads();
    float4 a0 = *(const float4*)(arow0 + kc + lk);
    float4 a1 = *(const float4*)(arow1 + kc + lk);
    float4 e0 = ev0 ? *(const float4*)(erow0 + kc + lk) : make_float4(0, 0, 0, 0);
    float4 e1 = ev1 ? *(const float4*)(erow1 + kc + lk) : make_float4(0, 0, 0, 0);
    Al[(lk + 0) * 68 + lr] = a0.x; Al[(lk + 1) * 68 + lr] = a0.y;
    Al[(lk + 2) * 68 + lr] = a0.z; Al[(lk + 3) * 68 + lr] = a0.w;
    Al[(lk + 0) * 68 + 32 + lr] = a1.x; Al[(lk + 1) * 68 + 32 + lr] = a1.y;
    Al[(lk + 2) * 68 + 32 + lr] = a1.z; Al[(lk + 3) * 68 + 32 + lr] = a1.w;
    El[(lk + 0) * 68 + lr] = e0.x; El[(lk + 1) * 68 + lr] = e0.y;
    El[(lk + 2) * 68 + lr] = e0.z; El[(lk + 3) * 68 + lr] = e0.w;
    El[(lk + 0) * 68 + 32 + lr] = e1.x; El[(lk + 1) * 68 + 32 + lr] = e1.y;
    El[(lk + 2) * 68 + 32 + lr] = e1.z; El[(lk + 3) * 68 + 32 + lr] = e1.w;
    __syncthreads();
    #pragma unroll
    for (int kk = 0; kk < 32; ++kk) {
      float4 av = *(const float4*)&Al[kk * 68 + ty * 4];
      float4 ev = *(const float4*)&El[kk * 68 + tx * 4];
      acc[0][0] += av.x * ev.x; acc[0][1] += av.x * ev.y; acc[0][2] += av.x * ev.z; acc[0][3] += av.x * ev.w;
      acc[1][0] += av.y * ev.x; acc[1][1] += av.y * ev.y; acc[1][2] += av.y * ev.z; acc[1][3] += av.y * ev.w;
      acc[2][0] += av.z * ev.x; acc[2][1] += av.z * ev.y; acc[2][2] += av.z * ev.z; acc[2][3] += av.z * ev.w;
      acc[3][0] += av.w * ev.x; acc[3][1] += av.w * ev.y; acc[3][2] += av.w * ev.z; acc[3][3] += av.w * ev.w;
    }
  }
  const int mbase = m0 + tx * 4;
  float w0 = (mbase + 0 < M_) ? invn[b * M_ + mbase + 0] : 0.f;
  float w1 = (mbase + 1 < M_) ? invn[b * M_ + mbase + 1] : 0.f;
  float w2 = (mbase + 2 < M_) ? invn[b * M_ + mbase + 2] : 0.f;
  float w3 = (mbase + 3 < M_) ? invn[b * M_ + mbase + 3] : 0.f;
  #pragma unroll
  for (int i = 0; i < 4; ++i) {
    int r = r0 + ty * 4 + i;
    float* crow = C + (size_t)(b * R_ + r) * M_;
    if (mbase + 3 < M_) {
      float4 o = make_float4(acc[i][0] * w0, acc[i][1] * w1, acc[i][2] * w2, acc[i][3] * w3);
      *(float4*)(crow + mbase) = o;
    } else {
      if (mbase + 0 < M_) crow[mbase + 0] = acc[i][0] * w0;
      if (mbase + 1 < M_) crow[mbase + 1] = acc[i][1] * w1;
      if (mbase + 2 < M_) crow[mbase + 2] = acc[i][2] * w2;
      if (mbase + 3 < M_) crow[mbase + 3] = acc[i][3] * w3;
    }
  }
}

// ---------------------------------------------------------------------------
// K3: top-4 per (b,r) row of C. Order doesn't matter downstream (sum over k),
// but use (value desc, index asc) comparator to match lax.top_k's tie rule.
__device__ __forceinline__ void topk_insert(float v, int m, float bv[4], int bi[4]) {
  bool better3 = (v > bv[3]) || (v == bv[3] && m < bi[3]);
  if (!better3) return;
  int pos = 3;
  while (pos > 0) {
    bool better = (v > bv[pos - 1]) || (v == bv[pos - 1] && m < bi[pos - 1]);
    if (better) { bv[pos] = bv[pos - 1]; bi[pos] = bi[pos - 1]; --pos; }
    else break;
  }
  bv[pos] = v; bi[pos] = m;
}

__global__ __launch_bounds__(256) void k_topk(const float* __restrict__ C,
                                              int* __restrict__ idxout) {
  int br = blockIdx.x;
  const float* row = C + (size_t)br * M_;
  int t = threadIdx.x;
  float bv[4] = {-FLT_MAX, -FLT_MAX, -FLT_MAX, -FLT_MAX};
  int   bi[4] = {0x7fffffff, 0x7fffffff, 0x7fffffff, 0x7fffffff};
  for (int m = t; m < M_; m += 256) topk_insert(row[m], m, bv, bi);
  __shared__ float sv[1024];
  __shared__ int   si[1024];
  #pragma unroll
  for (int q = 0; q < 4; ++q) { sv[t * 4 + q] = bv[q]; si[t * 4 + q] = bi[q]; }
  __syncthreads();
  if (t == 0) {
    float tv[4] = {-FLT_MAX, -FLT_MAX, -FLT_MAX, -FLT_MAX};
    int   ti[4] = {0x7fffffff, 0x7fffffff, 0x7fffffff, 0x7fffffff};
    for (int e = 0; e < 1024; ++e) topk_insert(sv[e], si[e], tv, ti);
    #pragma unroll
    for (int q = 0; q < 4; ++q) idxout[br * 4 + q] = ti[q];
  }
}

// ---------------------------------------------------------------------------
// K4: per (b,r,k) scalars: ||sim||^2, ref_t.sim, ref_s.sim, 1/max(||sim-ref_x||,eps)
__global__ __launch_bounds__(256) void k_prep(const float* __restrict__ teacher,
                                              const float* __restrict__ reft,
                                              const float* __restrict__ refs,
                                              const int* __restrict__ idx,
                                              float* __restrict__ prst,
                                              float* __restrict__ prss,
                                              float* __restrict__ pss,
                                              float* __restrict__ ib1t,
                                              float* __restrict__ ib1s) {
  int br = blockIdx.x;
  int b = br / R_;
  int w = threadIdx.x >> 6, lane = threadIdx.x & 63;
  int m = idx[br * 4 + w];
  int j = m / P_, p = m % P_;
  const float* sim = teacher + (((size_t)b * ST_ + 1 + 2 * j) * P_ + p) * D_;
  const float* rt = reft + (size_t)br * D_;
  const float* rs = refs + (size_t)br * D_;
  float s_ss = 0, s_rt = 0, s_rs = 0, s_dt = 0, s_ds = 0;
  #pragma unroll
  for (int it = 0; it < 4; ++it) {
    int d = (it * 64 + lane) * 4;
    float4 svv = *(const float4*)(sim + d);
    float4 tvv = *(const float4*)(rt + d);
    float4 uvv = *(const float4*)(rs + d);
    s_ss += dot4(svv, svv);
    s_rt += dot4(svv, tvv);
    s_rs += dot4(svv, uvv);
    float4 dt = make_float4(svv.x - tvv.x, svv.y - tvv.y, svv.z - tvv.z, svv.w - tvv.w);
    float4 ds = make_float4(svv.x - uvv.x, svv.y - uvv.y, svv.z - uvv.z, svv.w - uvv.w);
    s_dt += dot4(dt, dt);
    s_ds += dot4(ds, ds);
  }
  for (int o = 32; o; o >>= 1) {
    s_ss += __shfl_down(s_ss, o); s_rt += __shfl_down(s_rt, o); s_rs += __shfl_down(s_rs, o);
    s_dt += __shfl_down(s_dt, o); s_ds += __shfl_down(s_ds, o);
  }
  if (lane == 0) {
    int o = br * 4 + w;
    pss[o] = s_ss; prst[o] = s_rt; prss[o] = s_rs;
    ib1t[o] = 1.f / fmaxf(sqrtf(s_dt), 1e-8f);
    ib1s[o] = 1.f / fmaxf(sqrtf(s_ds), 1e-8f);
  }
}

// ---------------------------------------------------------------------------
// K5: fused loss. Block = (b*R + r, frame). Stage sim[4], ref_t, ref_s in LDS.
// Each wave handles strided s; 12 dot accumulators -> butterfly -> epilogue.
__device__ __forceinline__ float huber1(float d) {
  float ad = fabsf(d);
  return (ad < 1.0f) ? 0.5f * d * d : (ad - 0.5f);
}

__global__ __launch_bounds__(256) void k_loss(const float* __restrict__ teacher,
                                              const float* __restrict__ student,
                                              const int* __restrict__ shared_perm,
                                              const int* __restrict__ idx,
                                              const float* __restrict__ reft,
                                              const float* __restrict__ refs,
                                              const float* __restrict__ prrt,
                                              const float* __restrict__ prrs,
                                              const float* __restrict__ prst,
                                              const float* __restrict__ prss,
                                              const float* __restrict__ pss,
                                              const float* __restrict__ ib1t,
                                              const float* __restrict__ ib1s,
                                              float* __restrict__ out) {
  int br = blockIdx.x, f = blockIdx.y;
  int b = br / R_;
  int tf = 2 + 2 * f;   // teacher frames 2,4,6
  int sf = 1 + f;       // student frames 1,2,3
  __shared__ __align__(16) float Lsim[4][1024];
  __shared__ __align__(16) float Lrt[1024];
  __shared__ __align__(16) float Lrs[1024];
  __shared__ int sperm[128];
  __shared__ float scal[22];
  __shared__ float wred[4];
  int t = threadIdx.x;
  {
    const float* rt = reft + (size_t)br * D_;
    const float* rs = refs + (size_t)br * D_;
    *(float4*)&Lrt[t * 4] = *(const float4*)(rt + t * 4);
    *(float4*)&Lrs[t * 4] = *(const float4*)(rs + t * 4);
    #pragma unroll
    for (int k = 0; k < 4; ++k) {
      int m = idx[br * 4 + k]; int j = m / P_, p = m % P_;
      const float* sim = teacher + (((size_t)b * ST_ + 1 + 2 * j) * P_ + p) * D_;
      *(float4*)&Lsim[k][t * 4] = *(const float4*)(sim + t * 4);
    }
  }
  if (t < 128) sperm[t] = shared_perm[t];
  if (t < 4) {
    int o = br * 4 + t;
    scal[t] = prst[o]; scal[4 + t] = prss[o]; scal[8 + t] = pss[o];
    scal[12 + t] = ib1t[o]; scal[16 + t] = ib1s[o];
  }
  if (t == 4) scal[20] = prrt[br];
  if (t == 5) scal[21] = prrs[br];
  __syncthreads();

  int w = t >> 6, lane = t & 63;
  float lacc = 0.f;
  for (int s = w; s < NS_; s += 4) {
    int p = sperm[s];
    const float* sht = teacher + (((size_t)b * ST_ + tf) * P_ + p) * D_;
    const float* shs = student + (((size_t)b * SS_ + sf) * P_ + p) * D_;
    float qt[6] = {0, 0, 0, 0, 0, 0};   // [0..3]=sh_t.sim_k, [4]=sh_t.ref_t, [5]=||sh_t||^2
    float qs[6] = {0, 0, 0, 0, 0, 0};
    #pragma unroll
    for (int it = 0; it < 4; ++it) {
      int d = (it * 64 + lane) * 4;
      float4 a = *(const float4*)(sht + d);
      float4 c = *(const float4*)(shs + d);
      float4 r1 = *(const float4*)&Lrt[d];
      float4 r2 = *(const float4*)&Lrs[d];
      qt[4] += dot4(a, r1); qt[5] += dot4(a, a);
      qs[4] += dot4(c, r2); qs[5] += dot4(c, c);
      #pragma unroll
      for (int k = 0; k < 4; ++k) {
        float4 sv = *(const float4*)&Lsim[k][d];
        qt[k] += dot4(a, sv);
        qs[k] += dot4(c, sv);
      }
    }
    // butterfly allreduce across the wave (all lanes end with full sums)
    for (int o = 32; o; o >>= 1) {
      #pragma unroll
      for (int i = 0; i < 6; ++i) {
        qt[i] += __shfl_xor(qt[i], o);
        qs[i] += __shfl_xor(qs[i], o);
      }
    }
    if (lane < 4) {
      int k = lane;
      float Prs_t = scal[k], Prs_s = scal[4 + k], Pss_k = scal[8 + k];
      float ibt = scal[12 + k], ibs = scal[16 + k];
      float Prr_t = scal[20], Prr_s = scal[21];
      // teacher
      float qsim = qt[k], qref = qt[4], qss = qt[5];
      float n1sq = qss - 2.f * qref + Prr_t;
      float i1 = 1.f / fmaxf(sqrtf(fmaxf(n1sq, 0.f)), 1e-8f);
      float n2sq = qss - 2.f * qsim + Pss_k;
      float i2 = 1.f / fmaxf(sqrtf(fmaxf(n2sq, 0.f)), 1e-8f);
      float a1t = (qsim - qref - Prs_t + Prr_t) * ibt * i1;
      float a2t = -(qsim - Pss_k - qref + Prs_t) * ibt * i2;
      float a3t = (qss - qsim - qref + Prs_t) * i1 * i2;
      // student
      float qsimS = qs[k], qrefS = qs[4], qssS = qs[5];
      float n1sqS = qssS - 2.f * qrefS + Prr_s;
      float i1s = 1.f / fmaxf(sqrtf(fmaxf(n1sqS, 0.f)), 1e-8f);
      float n2sqS = qssS - 2.f * qsimS + Pss_k;
      float i2s = 1.f / fmaxf(sqrtf(fmaxf(n2sqS, 0.f)), 1e-8f);
      float a1s = (qsimS - qrefS - Prs_s + Prr_s) * ibs * i1s;
      float a2s = -(qsimS - Pss_k - qrefS + Prs_s) * ibs * i2s;
      float a3s = (qssS - qsimS - qrefS + Prs_s) * i1s * i2s;
      lacc += huber1(a1s - a1t) + huber1(a2s - a2t) + huber1(a3s - a3t);
    }
  }
  for (int o = 32; o; o >>= 1) lacc += __shfl_down(lacc, o);
  if (lane == 0) wred[w] = lacc;
  __syncthreads();
  if (t == 0) {
    float ssum = wred[0] + wred[1] + wred[2] + wred[3];
    atomicAdd(out, ssum * (1.0f / 393216.0f));  // /= B*R*NS*K*3 (W1=W2=W3=1)
  }
}

// ---------------------------------------------------------------------------
extern "C" void kernel_launch(void* const* d_in, const int* in_sizes, int n_in,
                              void* d_out, int out_size, void* d_ws, size_t ws_size,
                              hipStream_t stream) {
  const float* teacher = (const float*)d_in[0];
  const float* student = (const float*)d_in[1];
  const int* ref_perm = (const int*)d_in[2];
  const int* shared_perm = (const int*)d_in[3];
  float* ws = (float*)d_ws;
  float* invn = ws + OFF_INVN;
  float* reft = ws + OFF_REFT;
  float* refs = ws + OFF_REFS;
  float* prrt = ws + OFF_PRRT;
  float* prrs = ws + OFF_PRRS;
  float* C    = ws + OFF_C;
  int*   idx  = (int*)(ws + OFF_IDX);
  float* prst = ws + OFF_PRST;
  float* prss = ws + OFF_PRSS;
  float* pss  = ws + OFF_PSS;
  float* ib1t = ws + OFF_IB1T;
  float* ib1s = ws + OFF_IB1S;

  hipMemsetAsync(d_out, 0, sizeof(float), stream);

  k_extra_norms<<<(B_ * M_ + 3) / 4, 256, 0, stream>>>(teacher, invn);
  k_ref_gather<<<B_ * R_, 256, 0, stream>>>(teacher, student, ref_perm,
                                            reft, refs, prrt, prrs);
  k_sim_gemm<<<2 * 2 * 86, 256, 0, stream>>>(teacher, reft, invn, C);
  k_topk<<<B_ * R_, 256, 0, stream>>>(C, idx);
  k_prep<<<B_ * R_, 256, 0, stream>>>(teacher, reft, refs, idx,
                                      prst, prss, pss, ib1t, ib1s);
  k_loss<<<dim3(B_ * R_, 3), 256, 0, stream>>>(teacher, student, shared_perm, idx,
                                               reft, refs, prrt, prrs,
                                               prst, prss, pss, ib1t, ib1s,
                                               (float*)d_out);
}

// Round 2
// 417.430 us; speedup vs baseline: 1.2668x; 1.2668x over previous
//
#include <hip/hip_runtime.h>
#include <float.h>

// Problem constants
#define B_  2
#define ST_ 8      // teacher frames
#define SS_ 4      // student frames
#define P_  1369
#define D_  1024
#define R_  128
#define NS_ 128
#define K_  4
#define M_  5476   // 4 * P_ (extra frames 1,3,5,7 flattened)

// Workspace layout (float offsets). Total ~1.95M floats (~7.8 MB).
#define OFF_INVN  0u
#define OFF_REFT  11008u
#define OFF_REFS  (OFF_REFT + (unsigned)(B_*R_*D_))
#define OFF_PRRT  (OFF_REFS + (unsigned)(B_*R_*D_))
#define OFF_PRRS  (OFF_PRRT + 256u)
#define OFF_C     (OFF_PRRS + 256u)
#define OFF_IDX   (OFF_C + (unsigned)(B_*R_*M_))
#define OFF_PRST  (OFF_IDX + 1024u)
#define OFF_PRSS  (OFF_PRST + 1024u)
#define OFF_PSS   (OFF_PRSS + 1024u)
#define OFF_IB1T  (OFF_PSS + 1024u)
#define OFF_IB1S  (OFF_IB1T + 1024u)

__device__ __forceinline__ float dot4(const float4 a, const float4 b) {
  return a.x*b.x + a.y*b.y + a.z*b.z + a.w*b.w;
}

// ---------------------------------------------------------------------------
// K1: inverse norms of the 4 "extra" teacher frames' rows. One wave per row.
__global__ __launch_bounds__(256) void k_extra_norms(const float* __restrict__ teacher,
                                                     float* __restrict__ invn) {
  int row = blockIdx.x * 4 + (threadIdx.x >> 6);
  int lane = threadIdx.x & 63;
  if (row >= B_ * M_) return;
  int b = row / M_, m = row % M_;
  int j = m / P_, p = m % P_;                 // extra frame j -> teacher frame 1+2j
  const float* src = teacher + (((size_t)b * ST_ + 1 + 2 * j) * P_ + p) * D_;
  float s = 0.f;
  #pragma unroll
  for (int it = 0; it < 4; ++it) {
    float4 v = *(const float4*)(src + (it * 64 + lane) * 4);
    s += dot4(v, v);
  }
  for (int o = 32; o; o >>= 1) s += __shfl_down(s, o);
  if (lane == 0) invn[row] = 1.f / fmaxf(sqrtf(s), 1e-12f);
}

// ---------------------------------------------------------------------------
// K1b: gather ref_t / ref_s rows (frame 0, ref_perm) and their squared norms.
__global__ __launch_bounds__(256) void k_ref_gather(const float* __restrict__ teacher,
                                                    const float* __restrict__ student,
                                                    const int* __restrict__ ref_perm,
                                                    float* __restrict__ reft,
                                                    float* __restrict__ refs,
                                                    float* __restrict__ prrt,
                                                    float* __restrict__ prrs) {
  int br = blockIdx.x;          // b*R + r
  int b = br / R_, r = br % R_;
  int p = ref_perm[r];
  const float* st = teacher + (((size_t)b * ST_ + 0) * P_ + p) * D_;
  const float* ss = student + (((size_t)b * SS_ + 0) * P_ + p) * D_;
  float* dt = reft + (size_t)br * D_;
  float* dsp = refs + (size_t)br * D_;
  int t = threadIdx.x;
  float4 vt = *(const float4*)(st + t * 4);
  float4 vs = *(const float4*)(ss + t * 4);
  *(float4*)(dt + t * 4) = vt;
  *(float4*)(dsp + t * 4) = vs;
  float at = dot4(vt, vt);
  float as = dot4(vs, vs);
  for (int o = 32; o; o >>= 1) { at += __shfl_down(at, o); as += __shfl_down(as, o); }
  __shared__ float red[16];
  int w = t >> 6, lane = t & 63;
  if (lane == 0) { red[w] = at; red[8 + w] = as; }
  __syncthreads();
  if (t == 0) {
    prrt[br] = red[0] + red[1] + red[2] + red[3];
    prrs[br] = red[8] + red[9] + red[10] + red[11];
  }
}

// ---------------------------------------------------------------------------
// K2: C[b][r][m] = (ref_t[b,r] . extra[b,m]) * invn[b,m]
// 64x64 output tile per block, K-chunks of 32 staged transposed ([k][r]) in LDS.
__global__ __launch_bounds__(256) void k_sim_gemm(const float* __restrict__ teacher,
                                                  const float* __restrict__ reft,
                                                  const float* __restrict__ invn,
                                                  float* __restrict__ C) {
  const int bid = blockIdx.x;            // 2 * 2 * 86 = 344 blocks
  const int b   = bid / 172;
  const int rem = bid % 172;
  const int rt  = rem / 86;
  const int mt  = rem % 86;
  const int r0 = rt * 64, m0 = mt * 64;
  __shared__ __align__(16) float Al[32 * 68];   // [kk][r], stride 68
  __shared__ __align__(16) float El[32 * 68];
  const int t = threadIdx.x;
  const int tx = t & 15, ty = t >> 4;
  const int lr = t >> 3;                 // 0..31
  const int lk = (t & 7) * 4;            // 0,4,...,28
  const float* arow0 = reft + (size_t)(b * R_ + r0 + lr) * D_;
  const float* arow1 = reft + (size_t)(b * R_ + r0 + 32 + lr) * D_;
  const float* erow0; const float* erow1; bool ev0, ev1;
  {
    int m = m0 + lr; ev0 = m < M_;
    int mm = ev0 ? m : 0; int j = mm / P_, p = mm % P_;
    erow0 = teacher + (((size_t)b * ST_ + 1 + 2 * j) * P_ + p) * D_;
    m = m0 + 32 + lr; ev1 = m < M_;
    mm = ev1 ? m : 0; j = mm / P_; p = mm % P_;
    erow1 = teacher + (((size_t)b * ST_ + 1 + 2 * j) * P_ + p) * D_;
  }
  float acc[4][4];
  #pragma unroll
  for (int i = 0; i < 4; ++i)
    #pragma unroll
    for (int j = 0; j < 4; ++j) acc[i][j] = 0.f;

  for (int kc = 0; kc < D_; kc += 32) {
    __syncthreads();
    float4 a0 = *(const float4*)(arow0 + kc + lk);
    float4 a1 = *(const float4*)(arow1 + kc + lk);
    float4 e0 = ev0 ? *(const float4*)(erow0 + kc + lk) : make_float4(0, 0, 0, 0);
    float4 e1 = ev1 ? *(const float4*)(erow1 + kc + lk) : make_float4(0, 0, 0, 0);
    Al[(lk + 0) * 68 + lr] = a0.x; Al[(lk + 1) * 68 + lr] = a0.y;
    Al[(lk + 2) * 68 + lr] = a0.z; Al[(lk + 3) * 68 + lr] = a0.w;
    Al[(lk + 0) * 68 + 32 + lr] = a1.x; Al[(lk + 1) * 68 + 32 + lr] = a1.y;
    Al[(lk + 2) * 68 + 32 + lr] = a1.z; Al[(lk + 3) * 68 + 32 + lr] = a1.w;
    El[(lk + 0) * 68 + lr] = e0.x; El[(lk + 1) * 68 + lr] = e0.y;
    El[(lk + 2) * 68 + lr] = e0.z; El[(lk + 3) * 68 + lr] = e0.w;
    El[(lk + 0) * 68 + 32 + lr] = e1.x; El[(lk + 1) * 68 + 32 + lr] = e1.y;
    El[(lk + 2) * 68 + 32 + lr] = e1.z; El[(lk + 3) * 68 + 32 + lr] = e1.w;
    __syncthreads();
    #pragma unroll
    for (int kk = 0; kk < 32; ++kk) {
      float4 av = *(const float4*)&Al[kk * 68 + ty * 4];
      float4 ev = *(const float4*)&El[kk * 68 + tx * 4];
      acc[0][0] += av.x * ev.x; acc[0][1] += av.x * ev.y; acc[0][2] += av.x * ev.z; acc[0][3] += av.x * ev.w;
      acc[1][0] += av.y * ev.x; acc[1][1] += av.y * ev.y; acc[1][2] += av.y * ev.z; acc[1][3] += av.y * ev.w;
      acc[2][0] += av.z * ev.x; acc[2][1] += av.z * ev.y; acc[2][2] += av.z * ev.z; acc[2][3] += av.z * ev.w;
      acc[3][0] += av.w * ev.x; acc[3][1] += av.w * ev.y; acc[3][2] += av.w * ev.z; acc[3][3] += av.w * ev.w;
    }
  }
  const int mbase = m0 + tx * 4;
  float w0 = (mbase + 0 < M_) ? invn[b * M_ + mbase + 0] : 0.f;
  float w1 = (mbase + 1 < M_) ? invn[b * M_ + mbase + 1] : 0.f;
  float w2 = (mbase + 2 < M_) ? invn[b * M_ + mbase + 2] : 0.f;
  float w3 = (mbase + 3 < M_) ? invn[b * M_ + mbase + 3] : 0.f;
  #pragma unroll
  for (int i = 0; i < 4; ++i) {
    int r = r0 + ty * 4 + i;
    float* crow = C + (size_t)(b * R_ + r) * M_;
    if (mbase + 3 < M_) {
      float4 o = make_float4(acc[i][0] * w0, acc[i][1] * w1, acc[i][2] * w2, acc[i][3] * w3);
      *(float4*)(crow + mbase) = o;
    } else {
      if (mbase + 0 < M_) crow[mbase + 0] = acc[i][0] * w0;
      if (mbase + 1 < M_) crow[mbase + 1] = acc[i][1] * w1;
      if (mbase + 2 < M_) crow[mbase + 2] = acc[i][2] * w2;
      if (mbase + 3 < M_) crow[mbase + 3] = acc[i][3] * w3;
    }
  }
}

// ---------------------------------------------------------------------------
// K3: top-4 per (b,r) row of C.
// (value desc, index asc) comparator matches lax.top_k's tie rule.
// Parallel scheme: per-lane sorted top-4 -> 6-level shfl_xor butterfly merge
// (partners always hold candidates from DISJOINT element sets, so no index is
// ever merged with itself) -> 4 wave winners to LDS -> 16-entry serial merge.
__device__ __forceinline__ void topk_insert(float v, int m, float bv[4], int bi[4]) {
  bool better3 = (v > bv[3]) || (v == bv[3] && m < bi[3]);
  if (!better3) return;
  int pos = 3;
  while (pos > 0) {
    bool better = (v > bv[pos - 1]) || (v == bv[pos - 1] && m < bi[pos - 1]);
    if (better) { bv[pos] = bv[pos - 1]; bi[pos] = bi[pos - 1]; --pos; }
    else break;
  }
  bv[pos] = v; bi[pos] = m;
}

__global__ __launch_bounds__(256) void k_topk(const float* __restrict__ C,
                                              int* __restrict__ idxout) {
  int br = blockIdx.x;
  const float* row = C + (size_t)br * M_;
  int t = threadIdx.x;
  float bv[4] = {-FLT_MAX, -FLT_MAX, -FLT_MAX, -FLT_MAX};
  int   bi[4] = {0x7fffffff, 0x7fffffff, 0x7fffffff, 0x7fffffff};
  for (int m = t; m < M_; m += 256) topk_insert(row[m], m, bv, bi);

  // wave-level butterfly merge: all 64 lanes converge to the wave's top-4
  #pragma unroll
  for (int o = 1; o < 64; o <<= 1) {
    float ov[4]; int oi[4];
    #pragma unroll
    for (int q = 0; q < 4; ++q) {
      ov[q] = __shfl_xor(bv[q], o);
      oi[q] = __shfl_xor(bi[q], o);
    }
    #pragma unroll
    for (int q = 0; q < 4; ++q) topk_insert(ov[q], oi[q], bv, bi);
  }

  __shared__ float sv[16];
  __shared__ int   si[16];
  int w = t >> 6, lane = t & 63;
  if (lane == 0) {
    #pragma unroll
    for (int q = 0; q < 4; ++q) { sv[w * 4 + q] = bv[q]; si[w * 4 + q] = bi[q]; }
  }
  __syncthreads();
  if (t == 0) {
    float tv[4] = {-FLT_MAX, -FLT_MAX, -FLT_MAX, -FLT_MAX};
    int   ti[4] = {0x7fffffff, 0x7fffffff, 0x7fffffff, 0x7fffffff};
    #pragma unroll
    for (int e = 0; e < 16; ++e) topk_insert(sv[e], si[e], tv, ti);
    #pragma unroll
    for (int q = 0; q < 4; ++q) idxout[br * 4 + q] = ti[q];
  }
}

// ---------------------------------------------------------------------------
// K4: per (b,r,k) scalars: ||sim||^2, ref_t.sim, ref_s.sim, 1/max(||sim-ref_x||,eps)
__global__ __launch_bounds__(256) void k_prep(const float* __restrict__ teacher,
                                              const float* __restrict__ reft,
                                              const float* __restrict__ refs,
                                              const int* __restrict__ idx,
                                              float* __restrict__ prst,
                                              float* __restrict__ prss,
                                              float* __restrict__ pss,
                                              float* __restrict__ ib1t,
                                              float* __restrict__ ib1s) {
  int br = blockIdx.x;
  int b = br / R_;
  int w = threadIdx.x >> 6, lane = threadIdx.x & 63;
  int m = idx[br * 4 + w];
  int j = m / P_, p = m % P_;
  const float* sim = teacher + (((size_t)b * ST_ + 1 + 2 * j) * P_ + p) * D_;
  const float* rt = reft + (size_t)br * D_;
  const float* rs = refs + (size_t)br * D_;
  float s_ss = 0, s_rt = 0, s_rs = 0, s_dt = 0, s_ds = 0;
  #pragma unroll
  for (int it = 0; it < 4; ++it) {
    int d = (it * 64 + lane) * 4;
    float4 svv = *(const float4*)(sim + d);
    float4 tvv = *(const float4*)(rt + d);
    float4 uvv = *(const float4*)(rs + d);
    s_ss += dot4(svv, svv);
    s_rt += dot4(svv, tvv);
    s_rs += dot4(svv, uvv);
    float4 dt = make_float4(svv.x - tvv.x, svv.y - tvv.y, svv.z - tvv.z, svv.w - tvv.w);
    float4 ds = make_float4(svv.x - uvv.x, svv.y - uvv.y, svv.z - uvv.z, svv.w - uvv.w);
    s_dt += dot4(dt, dt);
    s_ds += dot4(ds, ds);
  }
  for (int o = 32; o; o >>= 1) {
    s_ss += __shfl_down(s_ss, o); s_rt += __shfl_down(s_rt, o); s_rs += __shfl_down(s_rs, o);
    s_dt += __shfl_down(s_dt, o); s_ds += __shfl_down(s_ds, o);
  }
  if (lane == 0) {
    int o = br * 4 + w;
    pss[o] = s_ss; prst[o] = s_rt; prss[o] = s_rs;
    ib1t[o] = 1.f / fmaxf(sqrtf(s_dt), 1e-8f);
    ib1s[o] = 1.f / fmaxf(sqrtf(s_ds), 1e-8f);
  }
}

// ---------------------------------------------------------------------------
// K5: fused loss. Block = (b*R + r, frame). Stage sim[4], ref_t, ref_s in LDS.
// Each wave handles strided s; 12 dot accumulators -> butterfly -> epilogue.
__device__ __forceinline__ float huber1(float d) {
  float ad = fabsf(d);
  return (ad < 1.0f) ? 0.5f * d * d : (ad - 0.5f);
}

__global__ __launch_bounds__(256) void k_loss(const float* __restrict__ teacher,
                                              const float* __restrict__ student,
                                              const int* __restrict__ shared_perm,
                                              const int* __restrict__ idx,
                                              const float* __restrict__ reft,
                                              const float* __restrict__ refs,
                                              const float* __restrict__ prrt,
                                              const float* __restrict__ prrs,
                                              const float* __restrict__ prst,
                                              const float* __restrict__ prss,
                                              const float* __restrict__ pss,
                                              const float* __restrict__ ib1t,
                                              const float* __restrict__ ib1s,
                                              float* __restrict__ out) {
  int br = blockIdx.x, f = blockIdx.y;
  int b = br / R_;
  int tf = 2 + 2 * f;   // teacher frames 2,4,6
  int sf = 1 + f;       // student frames 1,2,3
  __shared__ __align__(16) float Lsim[4][1024];
  __shared__ __align__(16) float Lrt[1024];
  __shared__ __align__(16) float Lrs[1024];
  __shared__ int sperm[128];
  __shared__ float scal[22];
  __shared__ float wred[4];
  int t = threadIdx.x;
  {
    const float* rt = reft + (size_t)br * D_;
    const float* rs = refs + (size_t)br * D_;
    *(float4*)&Lrt[t * 4] = *(const float4*)(rt + t * 4);
    *(float4*)&Lrs[t * 4] = *(const float4*)(rs + t * 4);
    #pragma unroll
    for (int k = 0; k < 4; ++k) {
      int m = idx[br * 4 + k]; int j = m / P_, p = m % P_;
      const float* sim = teacher + (((size_t)b * ST_ + 1 + 2 * j) * P_ + p) * D_;
      *(float4*)&Lsim[k][t * 4] = *(const float4*)(sim + t * 4);
    }
  }
  if (t < 128) sperm[t] = shared_perm[t];
  if (t < 4) {
    int o = br * 4 + t;
    scal[t] = prst[o]; scal[4 + t] = prss[o]; scal[8 + t] = pss[o];
    scal[12 + t] = ib1t[o]; scal[16 + t] = ib1s[o];
  }
  if (t == 4) scal[20] = prrt[br];
  if (t == 5) scal[21] = prrs[br];
  __syncthreads();

  int w = t >> 6, lane = t & 63;
  float lacc = 0.f;
  for (int s = w; s < NS_; s += 4) {
    int p = sperm[s];
    const float* sht = teacher + (((size_t)b * ST_ + tf) * P_ + p) * D_;
    const float* shs = student + (((size_t)b * SS_ + sf) * P_ + p) * D_;
    float qt[6] = {0, 0, 0, 0, 0, 0};   // [0..3]=sh_t.sim_k, [4]=sh_t.ref_t, [5]=||sh_t||^2
    float qs[6] = {0, 0, 0, 0, 0, 0};
    #pragma unroll
    for (int it = 0; it < 4; ++it) {
      int d = (it * 64 + lane) * 4;
      float4 a = *(const float4*)(sht + d);
      float4 c = *(const float4*)(shs + d);
      float4 r1 = *(const float4*)&Lrt[d];
      float4 r2 = *(const float4*)&Lrs[d];
      qt[4] += dot4(a, r1); qt[5] += dot4(a, a);
      qs[4] += dot4(c, r2); qs[5] += dot4(c, c);
      #pragma unroll
      for (int k = 0; k < 4; ++k) {
        float4 sv = *(const float4*)&Lsim[k][d];
        qt[k] += dot4(a, sv);
        qs[k] += dot4(c, sv);
      }
    }
    // butterfly allreduce across the wave (all lanes end with full sums)
    for (int o = 32; o; o >>= 1) {
      #pragma unroll
      for (int i = 0; i < 6; ++i) {
        qt[i] += __shfl_xor(qt[i], o);
        qs[i] += __shfl_xor(qs[i], o);
      }
    }
    if (lane < 4) {
      int k = lane;
      float Prs_t = scal[k], Prs_s = scal[4 + k], Pss_k = scal[8 + k];
      float ibt = scal[12 + k], ibs = scal[16 + k];
      float Prr_t = scal[20], Prr_s = scal[21];
      // teacher
      float qsim = qt[k], qref = qt[4], qss = qt[5];
      float n1sq = qss - 2.f * qref + Prr_t;
      float i1 = 1.f / fmaxf(sqrtf(fmaxf(n1sq, 0.f)), 1e-8f);
      float n2sq = qss - 2.f * qsim + Pss_k;
      float i2 = 1.f / fmaxf(sqrtf(fmaxf(n2sq, 0.f)), 1e-8f);
      float a1t = (qsim - qref - Prs_t + Prr_t) * ibt * i1;
      float a2t = -(qsim - Pss_k - qref + Prs_t) * ibt * i2;
      float a3t = (qss - qsim - qref + Prs_t) * i1 * i2;
      // student
      float qsimS = qs[k], qrefS = qs[4], qssS = qs[5];
      float n1sqS = qssS - 2.f * qrefS + Prr_s;
      float i1s = 1.f / fmaxf(sqrtf(fmaxf(n1sqS, 0.f)), 1e-8f);
      float n2sqS = qssS - 2.f * qsimS + Pss_k;
      float i2s = 1.f / fmaxf(sqrtf(fmaxf(n2sqS, 0.f)), 1e-8f);
      float a1s = (qsimS - qrefS - Prs_s + Prr_s) * ibs * i1s;
      float a2s = -(qsimS - Pss_k - qrefS + Prs_s) * ibs * i2s;
      float a3s = (qssS - qsimS - qrefS + Prs_s) * i1s * i2s;
      lacc += huber1(a1s - a1t) + huber1(a2s - a2t) + huber1(a3s - a3t);
    }
  }
  for (int o = 32; o; o >>= 1) lacc += __shfl_down(lacc, o);
  if (lane == 0) wred[w] = lacc;
  __syncthreads();
  if (t == 0) {
    float ssum = wred[0] + wred[1] + wred[2] + wred[3];
    atomicAdd(out, ssum * (1.0f / 393216.0f));  // /= B*R*NS*K*3 (W1=W2=W3=1)
  }
}

// ---------------------------------------------------------------------------
extern "C" void kernel_launch(void* const* d_in, const int* in_sizes, int n_in,
                              void* d_out, int out_size, void* d_ws, size_t ws_size,
                              hipStream_t stream) {
  const float* teacher = (const float*)d_in[0];
  const float* student = (const float*)d_in[1];
  const int* ref_perm = (const int*)d_in[2];
  const int* shared_perm = (const int*)d_in[3];
  float* ws = (float*)d_ws;
  float* invn = ws + OFF_INVN;
  float* reft = ws + OFF_REFT;
  float* refs = ws + OFF_REFS;
  float* prrt = ws + OFF_PRRT;
  float* prrs = ws + OFF_PRRS;
  float* C    = ws + OFF_C;
  int*   idx  = (int*)(ws + OFF_IDX);
  float* prst = ws + OFF_PRST;
  float* prss = ws + OFF_PRSS;
  float* pss  = ws + OFF_PSS;
  float* ib1t = ws + OFF_IB1T;
  float* ib1s = ws + OFF_IB1S;

  hipMemsetAsync(d_out, 0, sizeof(float), stream);

  k_extra_norms<<<(B_ * M_ + 3) / 4, 256, 0, stream>>>(teacher, invn);
  k_ref_gather<<<B_ * R_, 256, 0, stream>>>(teacher, student, ref_perm,
                                            reft, refs, prrt, prrs);
  k_sim_gemm<<<2 * 2 * 86, 256, 0, stream>>>(teacher, reft, invn, C);
  k_topk<<<B_ * R_, 256, 0, stream>>>(C, idx);
  k_prep<<<B_ * R_, 256, 0, stream>>>(teacher, reft, refs, idx,
                                      prst, prss, pss, ib1t, ib1s);
  k_loss<<<dim3(B_ * R_, 3), 256, 0, stream>>>(teacher, student, shared_perm, idx,
                                               reft, refs, prrt, prrs,
                                               prst, prss, pss, ib1t, ib1s,
                                               (float*)d_out);
}

// Round 4
// 343.149 us; speedup vs baseline: 1.5410x; 1.2165x over previous
//
#include <hip/hip_runtime.h>
#include <float.h>

// Problem constants
#define B_  2
#define ST_ 8      // teacher frames
#define SS_ 4      // student frames
#define P_  1369
#define D_  1024
#define R_  128
#define NS_ 128
#define K_  4
#define M_  5476   // 4 * P_ (extra frames 1,3,5,7 flattened)

// Workspace layout (float offsets). Total ~1.95M floats (~7.8 MB).
#define OFF_INVN  0u
#define OFF_REFT  11008u
#define OFF_REFS  (OFF_REFT + (unsigned)(B_*R_*D_))
#define OFF_PRRT  (OFF_REFS + (unsigned)(B_*R_*D_))
#define OFF_PRRS  (OFF_PRRT + 256u)
#define OFF_C     (OFF_PRRS + 256u)
#define OFF_IDX   (OFF_C + (unsigned)(B_*R_*M_))
#define OFF_PRST  (OFF_IDX + 1024u)
#define OFF_PRSS  (OFF_PRST + 1024u)
#define OFF_PSS   (OFF_PRSS + 1024u)
#define OFF_IB1T  (OFF_PSS + 1024u)
#define OFF_IB1S  (OFF_IB1T + 1024u)
#define OFF_NSH   (OFF_IB1S + 1024u)   // 1536 floats: [0..767] teacher ||sh||^2, [768..1535] student

__device__ __forceinline__ float dot4(const float4 a, const float4 b) {
  return a.x*b.x + a.y*b.y + a.z*b.z + a.w*b.w;
}

// ---------------------------------------------------------------------------
// K1: inverse norms of the 4 "extra" teacher frames' rows. One wave per row.
__global__ __launch_bounds__(256) void k_extra_norms(const float* __restrict__ teacher,
                                                     float* __restrict__ invn) {
  int row = blockIdx.x * 4 + (threadIdx.x >> 6);
  int lane = threadIdx.x & 63;
  if (row >= B_ * M_) return;
  int b = row / M_, m = row % M_;
  int j = m / P_, p = m % P_;                 // extra frame j -> teacher frame 1+2j
  const float* src = teacher + (((size_t)b * ST_ + 1 + 2 * j) * P_ + p) * D_;
  float s = 0.f;
  #pragma unroll
  for (int it = 0; it < 4; ++it) {
    float4 v = *(const float4*)(src + (it * 64 + lane) * 4);
    s += dot4(v, v);
  }
  for (int o = 32; o; o >>= 1) s += __shfl_down(s, o);
  if (lane == 0) invn[row] = 1.f / fmaxf(sqrtf(s), 1e-12f);
}

// ---------------------------------------------------------------------------
// K1c: squared norms of the shared rows used by k_loss (no r dependence —
// previously recomputed 128x per r inside k_loss). 1536 rows, one wave each.
__global__ __launch_bounds__(256) void k_shnorm(const float* __restrict__ teacher,
                                                const float* __restrict__ student,
                                                const int* __restrict__ shared_perm,
                                                float* __restrict__ nsh) {
  int row = blockIdx.x * 4 + (threadIdx.x >> 6);
  int lane = threadIdx.x & 63;
  if (row >= 2 * B_ * 3 * NS_) return;
  int rid = row % (B_ * 3 * NS_);
  int is_stu = row / (B_ * 3 * NS_);
  int b = rid / (3 * NS_);
  int rem = rid % (3 * NS_);
  int f = rem / NS_, s = rem % NS_;
  int p = shared_perm[s];
  const float* src = is_stu
      ? student + (((size_t)b * SS_ + 1 + f) * P_ + p) * D_
      : teacher + (((size_t)b * ST_ + 2 + 2 * f) * P_ + p) * D_;
  float acc = 0.f;
  #pragma unroll
  for (int it = 0; it < 4; ++it) {
    float4 v = *(const float4*)(src + (it * 64 + lane) * 4);
    acc += dot4(v, v);
  }
  for (int o = 32; o; o >>= 1) acc += __shfl_down(acc, o);
  if (lane == 0) nsh[row] = acc;
}

// ---------------------------------------------------------------------------
// K1b: gather ref_t / ref_s rows (frame 0, ref_perm) and their squared norms.
__global__ __launch_bounds__(256) void k_ref_gather(const float* __restrict__ teacher,
                                                    const float* __restrict__ student,
                                                    const int* __restrict__ ref_perm,
                                                    float* __restrict__ reft,
                                                    float* __restrict__ refs,
                                                    float* __restrict__ prrt,
                                                    float* __restrict__ prrs) {
  int br = blockIdx.x;          // b*R + r
  int b = br / R_, r = br % R_;
  int p = ref_perm[r];
  const float* st = teacher + (((size_t)b * ST_ + 0) * P_ + p) * D_;
  const float* ss = student + (((size_t)b * SS_ + 0) * P_ + p) * D_;
  float* dt = reft + (size_t)br * D_;
  float* dsp = refs + (size_t)br * D_;
  int t = threadIdx.x;
  float4 vt = *(const float4*)(st + t * 4);
  float4 vs = *(const float4*)(ss + t * 4);
  *(float4*)(dt + t * 4) = vt;
  *(float4*)(dsp + t * 4) = vs;
  float at = dot4(vt, vt);
  float as = dot4(vs, vs);
  for (int o = 32; o; o >>= 1) { at += __shfl_down(at, o); as += __shfl_down(as, o); }
  __shared__ float red[16];
  int w = t >> 6, lane = t & 63;
  if (lane == 0) { red[w] = at; red[8 + w] = as; }
  __syncthreads();
  if (t == 0) {
    prrt[br] = red[0] + red[1] + red[2] + red[3];
    prrs[br] = red[8] + red[9] + red[10] + red[11];
  }
}

// ---------------------------------------------------------------------------
// K2: C[b][r][m] += partial (ref_t[b,r] . extra[b,m]) over half the K range.
// Split-K x2: 688 blocks (2.7/CU). Exactly two fp32 atomic contributions per
// element (commutative -> deterministic). invn scaling moved to k_topk.
__global__ __launch_bounds__(256) void k_sim_gemm(const float* __restrict__ teacher,
                                                  const float* __restrict__ reft,
                                                  float* __restrict__ C) {
  const int bid = blockIdx.x;            // 2(b) * 2(rt) * 86(mt) * 2(kh) = 688
  const int kh  = bid & 1;
  const int rest = bid >> 1;
  const int b   = rest / 172;
  const int rem = rest % 172;
  const int rt  = rem / 86;
  const int mt  = rem % 86;
  const int r0 = rt * 64, m0 = mt * 64;
  __shared__ __align__(16) float Al[32 * 68];   // [kk][r], stride 68
  __shared__ __align__(16) float El[32 * 68];
  const int t = threadIdx.x;
  const int tx = t & 15, ty = t >> 4;
  const int lr = t >> 3;                 // 0..31
  const int lk = (t & 7) * 4;            // 0,4,...,28
  const float* arow0 = reft + (size_t)(b * R_ + r0 + lr) * D_;
  const float* arow1 = reft + (size_t)(b * R_ + r0 + 32 + lr) * D_;
  const float* erow0; const float* erow1; bool ev0, ev1;
  {
    int m = m0 + lr; ev0 = m < M_;
    int mm = ev0 ? m : 0; int j = mm / P_, p = mm % P_;
    erow0 = teacher + (((size_t)b * ST_ + 1 + 2 * j) * P_ + p) * D_;
    m = m0 + 32 + lr; ev1 = m < M_;
    mm = ev1 ? m : 0; j = mm / P_; p = mm % P_;
    erow1 = teacher + (((size_t)b * ST_ + 1 + 2 * j) * P_ + p) * D_;
  }
  float acc[4][4];
  #pragma unroll
  for (int i = 0; i < 4; ++i)
    #pragma unroll
    for (int j = 0; j < 4; ++j) acc[i][j] = 0.f;

  const int kbeg = kh * 512, kend = kbeg + 512;
  for (int kc = kbeg; kc < kend; kc += 32) {
    __syncthreads();
    float4 a0 = *(const float4*)(arow0 + kc + lk);
    float4 a1 = *(const float4*)(arow1 + kc + lk);
    float4 e0 = ev0 ? *(const float4*)(erow0 + kc + lk) : make_float4(0, 0, 0, 0);
    float4 e1 = ev1 ? *(const float4*)(erow1 + kc + lk) : make_float4(0, 0, 0, 0);
    Al[(lk + 0) * 68 + lr] = a0.x; Al[(lk + 1) * 68 + lr] = a0.y;
    Al[(lk + 2) * 68 + lr] = a0.z; Al[(lk + 3) * 68 + lr] = a0.w;
    Al[(lk + 0) * 68 + 32 + lr] = a1.x; Al[(lk + 1) * 68 + 32 + lr] = a1.y;
    Al[(lk + 2) * 68 + 32 + lr] = a1.z; Al[(lk + 3) * 68 + 32 + lr] = a1.w;
    El[(lk + 0) * 68 + lr] = e0.x; El[(lk + 1) * 68 + lr] = e0.y;
    El[(lk + 2) * 68 + lr] = e0.z; El[(lk + 3) * 68 + lr] = e0.w;
    El[(lk + 0) * 68 + 32 + lr] = e1.x; El[(lk + 1) * 68 + 32 + lr] = e1.y;
    El[(lk + 2) * 68 + 32 + lr] = e1.z; El[(lk + 3) * 68 + 32 + lr] = e1.w;
    __syncthreads();
    #pragma unroll
    for (int kk = 0; kk < 32; ++kk) {
      float4 av = *(const float4*)&Al[kk * 68 + ty * 4];
      float4 ev = *(const float4*)&El[kk * 68 + tx * 4];
      acc[0][0] += av.x * ev.x; acc[0][1] += av.x * ev.y; acc[0][2] += av.x * ev.z; acc[0][3] += av.x * ev.w;
      acc[1][0] += av.y * ev.x; acc[1][1] += av.y * ev.y; acc[1][2] += av.y * ev.z; acc[1][3] += av.y * ev.w;
      acc[2][0] += av.z * ev.x; acc[2][1] += av.z * ev.y; acc[2][2] += av.z * ev.z; acc[2][3] += av.z * ev.w;
      acc[3][0] += av.w * ev.x; acc[3][1] += av.w * ev.y; acc[3][2] += av.w * ev.z; acc[3][3] += av.w * ev.w;
    }
  }
  const int mbase = m0 + tx * 4;
  #pragma unroll
  for (int i = 0; i < 4; ++i) {
    int r = r0 + ty * 4 + i;
    float* crow = C + (size_t)(b * R_ + r) * M_;
    #pragma unroll
    for (int q = 0; q < 4; ++q) {
      if (mbase + q < M_) atomicAdd(&crow[mbase + q], acc[i][q]);
    }
  }
}

// ---------------------------------------------------------------------------
// K3: top-4 per (b,r) row of C (scaled on the fly by invn[m], a positive
// per-m factor). (value desc, index asc) comparator matches lax.top_k.
__device__ __forceinline__ void topk_insert(float v, int m, float bv[4], int bi[4]) {
  bool better3 = (v > bv[3]) || (v == bv[3] && m < bi[3]);
  if (!better3) return;
  int pos = 3;
  while (pos > 0) {
    bool better = (v > bv[pos - 1]) || (v == bv[pos - 1] && m < bi[pos - 1]);
    if (better) { bv[pos] = bv[pos - 1]; bi[pos] = bi[pos - 1]; --pos; }
    else break;
  }
  bv[pos] = v; bi[pos] = m;
}

__global__ __launch_bounds__(256) void k_topk(const float* __restrict__ C,
                                              const float* __restrict__ invn,
                                              int* __restrict__ idxout) {
  int br = blockIdx.x;
  int b = br / R_;
  const float* row = C + (size_t)br * M_;
  const float* w = invn + (size_t)b * M_;
  int t = threadIdx.x;
  float bv[4] = {-FLT_MAX, -FLT_MAX, -FLT_MAX, -FLT_MAX};
  int   bi[4] = {0x7fffffff, 0x7fffffff, 0x7fffffff, 0x7fffffff};
  for (int m = t; m < M_; m += 256) topk_insert(row[m] * w[m], m, bv, bi);

  // wave-level butterfly merge: all 64 lanes converge to the wave's top-4
  #pragma unroll
  for (int o = 1; o < 64; o <<= 1) {
    float ov[4]; int oi[4];
    #pragma unroll
    for (int q = 0; q < 4; ++q) {
      ov[q] = __shfl_xor(bv[q], o);
      oi[q] = __shfl_xor(bi[q], o);
    }
    #pragma unroll
    for (int q = 0; q < 4; ++q) topk_insert(ov[q], oi[q], bv, bi);
  }

  __shared__ float sv[16];
  __shared__ int   si[16];
  int wv = t >> 6, lane = t & 63;
  if (lane == 0) {
    #pragma unroll
    for (int q = 0; q < 4; ++q) { sv[wv * 4 + q] = bv[q]; si[wv * 4 + q] = bi[q]; }
  }
  __syncthreads();
  if (t == 0) {
    float tv[4] = {-FLT_MAX, -FLT_MAX, -FLT_MAX, -FLT_MAX};
    int   ti[4] = {0x7fffffff, 0x7fffffff, 0x7fffffff, 0x7fffffff};
    #pragma unroll
    for (int e = 0; e < 16; ++e) topk_insert(sv[e], si[e], tv, ti);
    #pragma unroll
    for (int q = 0; q < 4; ++q) idxout[br * 4 + q] = ti[q];
  }
}

// ---------------------------------------------------------------------------
// K4: per (b,r,k) scalars: ||sim||^2, ref_t.sim, ref_s.sim, 1/max(||sim-ref_x||,eps)
__global__ __launch_bounds__(256) void k_prep(const float* __restrict__ teacher,
                                              const float* __restrict__ reft,
                                              const float* __restrict__ refs,
                                              const int* __restrict__ idx,
                                              float* __restrict__ prst,
                                              float* __restrict__ prss,
                                              float* __restrict__ pss,
                                              float* __restrict__ ib1t,
                                              float* __restrict__ ib1s) {
  int br = blockIdx.x;
  int b = br / R_;
  int w = threadIdx.x >> 6, lane = threadIdx.x & 63;
  int m = idx[br * 4 + w];
  int j = m / P_, p = m % P_;
  const float* sim = teacher + (((size_t)b * ST_ + 1 + 2 * j) * P_ + p) * D_;
  const float* rt = reft + (size_t)br * D_;
  const float* rs = refs + (size_t)br * D_;
  float s_ss = 0, s_rt = 0, s_rs = 0, s_dt = 0, s_ds = 0;
  #pragma unroll
  for (int it = 0; it < 4; ++it) {
    int d = (it * 64 + lane) * 4;
    float4 svv = *(const float4*)(sim + d);
    float4 tvv = *(const float4*)(rt + d);
    float4 uvv = *(const float4*)(rs + d);
    s_ss += dot4(svv, svv);
    s_rt += dot4(svv, tvv);
    s_rs += dot4(svv, uvv);
    float4 dt = make_float4(svv.x - tvv.x, svv.y - tvv.y, svv.z - tvv.z, svv.w - tvv.w);
    float4 ds = make_float4(svv.x - uvv.x, svv.y - uvv.y, svv.z - uvv.z, svv.w - uvv.w);
    s_dt += dot4(dt, dt);
    s_ds += dot4(ds, ds);
  }
  for (int o = 32; o; o >>= 1) {
    s_ss += __shfl_down(s_ss, o); s_rt += __shfl_down(s_rt, o); s_rs += __shfl_down(s_rs, o);
    s_dt += __shfl_down(s_dt, o); s_ds += __shfl_down(s_ds, o);
  }
  if (lane == 0) {
    int o = br * 4 + w;
    pss[o] = s_ss; prst[o] = s_rt; prss[o] = s_rs;
    ib1t[o] = 1.f / fmaxf(sqrtf(s_dt), 1e-8f);
    ib1s[o] = 1.f / fmaxf(sqrtf(s_ds), 1e-8f);
  }
}

// ---------------------------------------------------------------------------
// K5 v2: fused loss. Block = (br, frame, s-chunk of 64). 64 groups of 4 lanes;
// each group owns one s, each lane one k. 2-level reduce instead of 6-level.
__device__ __forceinline__ float huber1(float d) {
  float ad = fabsf(d);
  return (ad < 1.0f) ? 0.5f * d * d : (ad - 0.5f);
}

__global__ __launch_bounds__(256) void k_loss(const float* __restrict__ teacher,
                                              const float* __restrict__ student,
                                              const int* __restrict__ shared_perm,
                                              const int* __restrict__ idx,
                                              const float* __restrict__ reft,
                                              const float* __restrict__ refs,
                                              const float* __restrict__ prrt,
                                              const float* __restrict__ prrs,
                                              const float* __restrict__ prst,
                                              const float* __restrict__ prss,
                                              const float* __restrict__ pss,
                                              const float* __restrict__ ib1t,
                                              const float* __restrict__ ib1s,
                                              const float* __restrict__ nsh,
                                              float* __restrict__ out) {
  int br = blockIdx.x, f = blockIdx.y, sc = blockIdx.z;
  int b = br / R_;
  int tf = 2 + 2 * f;   // teacher frames 2,4,6
  int sf = 1 + f;       // student frames 1,2,3
  __shared__ __align__(16) float Lsim[4][1024];
  __shared__ __align__(16) float Lrt[1024];
  __shared__ __align__(16) float Lrs[1024];
  __shared__ int sperm[128];
  __shared__ float Lns[2][64];
  __shared__ float scal[22];
  __shared__ float wred[4];
  int t = threadIdx.x;
  {
    const float* rt = reft + (size_t)br * D_;
    const float* rs = refs + (size_t)br * D_;
    *(float4*)&Lrt[t * 4] = *(const float4*)(rt + t * 4);
    *(float4*)&Lrs[t * 4] = *(const float4*)(rs + t * 4);
    #pragma unroll
    for (int k = 0; k < 4; ++k) {
      int m = idx[br * 4 + k]; int j = m / P_, p = m % P_;
      const float* sim = teacher + (((size_t)b * ST_ + 1 + 2 * j) * P_ + p) * D_;
      *(float4*)&Lsim[k][t * 4] = *(const float4*)(sim + t * 4);
    }
  }
  if (t < 128) sperm[t] = shared_perm[t];
  if (t < 64) {
    int o = (b * 3 + f) * NS_ + sc * 64 + t;
    Lns[0][t] = nsh[o];
    Lns[1][t] = nsh[B_ * 3 * NS_ + o];
  }
  if (t < 4) {
    int o = br * 4 + t;
    scal[t] = prst[o]; scal[4 + t] = prss[o]; scal[8 + t] = pss[o];
    scal[12 + t] = ib1t[o]; scal[16 + t] = ib1s[o];
  }
  if (t == 4) scal[20] = prrt[br];
  if (t == 5) scal[21] = prrs[br];
  __syncthreads();

  const int g = t >> 2, gl = t & 3;
  const int s = sc * 64 + g;
  const int p = sperm[s];
  const float* sht = teacher + (((size_t)b * ST_ + tf) * P_ + p) * D_;
  const float* shs = student + (((size_t)b * SS_ + sf) * P_ + p) * D_;

  float qt0 = 0, qt1 = 0, qt2 = 0, qt3 = 0, qtr = 0;
  float qs0 = 0, qs1 = 0, qs2 = 0, qs3 = 0, qsr = 0;
  #pragma unroll 2
  for (int i = 0; i < 64; ++i) {
    int off = i * 16 + gl * 4;
    float4 a  = *(const float4*)(sht + off);
    float4 c  = *(const float4*)(shs + off);
    float4 v0 = *(const float4*)&Lsim[0][off];
    float4 v1 = *(const float4*)&Lsim[1][off];
    float4 v2 = *(const float4*)&Lsim[2][off];
    float4 v3 = *(const float4*)&Lsim[3][off];
    float4 r1 = *(const float4*)&Lrt[off];
    float4 r2 = *(const float4*)&Lrs[off];
    qt0 += dot4(a, v0); qt1 += dot4(a, v1); qt2 += dot4(a, v2); qt3 += dot4(a, v3);
    qtr += dot4(a, r1);
    qs0 += dot4(c, v0); qs1 += dot4(c, v1); qs2 += dot4(c, v2); qs3 += dot4(c, v3);
    qsr += dot4(c, r2);
  }
  // 2-level butterfly within the 4-lane group
  #pragma unroll
  for (int o = 1; o <= 2; o <<= 1) {
    qt0 += __shfl_xor(qt0, o); qt1 += __shfl_xor(qt1, o);
    qt2 += __shfl_xor(qt2, o); qt3 += __shfl_xor(qt3, o);
    qtr += __shfl_xor(qtr, o);
    qs0 += __shfl_xor(qs0, o); qs1 += __shfl_xor(qs1, o);
    qs2 += __shfl_xor(qs2, o); qs3 += __shfl_xor(qs3, o);
    qsr += __shfl_xor(qsr, o);
  }
  // lane gl handles k = gl (static selects, no scratch)
  const int k = gl;
  float qsim  = (gl == 0) ? qt0 : (gl == 1) ? qt1 : (gl == 2) ? qt2 : qt3;
  float qsimS = (gl == 0) ? qs0 : (gl == 1) ? qs1 : (gl == 2) ? qs2 : qs3;
  float qref = qtr, qrefS = qsr;
  float qss = Lns[0][g], qssS = Lns[1][g];

  float Prs_t = scal[k], Prs_s = scal[4 + k], Pss_k = scal[8 + k];
  float ibt = scal[12 + k], ibs = scal[16 + k];
  float Prr_t = scal[20], Prr_s = scal[21];
  // teacher
  float n1sq = qss - 2.f * qref + Prr_t;
  float i1 = 1.f / fmaxf(sqrtf(fmaxf(n1sq, 0.f)), 1e-8f);
  float n2sq = qss - 2.f * qsim + Pss_k;
  float i2 = 1.f / fmaxf(sqrtf(fmaxf(n2sq, 0.f)), 1e-8f);
  float a1t = (qsim - qref - Prs_t + Prr_t) * ibt * i1;
  float a2t = -(qsim - Pss_k - qref + Prs_t) * ibt * i2;
  float a3t = (qss - qsim - qref + Prs_t) * i1 * i2;
  // student
  float n1sqS = qssS - 2.f * qrefS + Prr_s;
  float i1s = 1.f / fmaxf(sqrtf(fmaxf(n1sqS, 0.f)), 1e-8f);
  float n2sqS = qssS - 2.f * qsimS + Pss_k;
  float i2s = 1.f / fmaxf(sqrtf(fmaxf(n2sqS, 0.f)), 1e-8f);
  float a1s = (qsimS - qrefS - Prs_s + Prr_s) * ibs * i1s;
  float a2s = -(qsimS - Pss_k - qrefS + Prs_s) * ibs * i2s;
  float a3s = (qssS - qsimS - qrefS + Prs_s) * i1s * i2s;
  float lacc = huber1(a1s - a1t) + huber1(a2s - a2t) + huber1(a3s - a3t);

  // block reduction
  int w = t >> 6, lane = t & 63;
  for (int o = 32; o; o >>= 1) lacc += __shfl_down(lacc, o);
  if (lane == 0) wred[w] = lacc;
  __syncthreads();
  if (t == 0) {
    float ssum = wred[0] + wred[1] + wred[2] + wred[3];
    atomicAdd(out, ssum * (1.0f / 393216.0f));  // /= B*R*NS*K*3 (W1=W2=W3=1)
  }
}

// ---------------------------------------------------------------------------
extern "C" void kernel_launch(void* const* d_in, const int* in_sizes, int n_in,
                              void* d_out, int out_size, void* d_ws, size_t ws_size,
                              hipStream_t stream) {
  const float* teacher = (const float*)d_in[0];
  const float* student = (const float*)d_in[1];
  const int* ref_perm = (const int*)d_in[2];
  const int* shared_perm = (const int*)d_in[3];
  float* ws = (float*)d_ws;
  float* invn = ws + OFF_INVN;
  float* reft = ws + OFF_REFT;
  float* refs = ws + OFF_REFS;
  float* prrt = ws + OFF_PRRT;
  float* prrs = ws + OFF_PRRS;
  float* C    = ws + OFF_C;
  int*   idx  = (int*)(ws + OFF_IDX);
  float* prst = ws + OFF_PRST;
  float* prss = ws + OFF_PRSS;
  float* pss  = ws + OFF_PSS;
  float* ib1t = ws + OFF_IB1T;
  float* ib1s = ws + OFF_IB1S;
  float* nsh  = ws + OFF_NSH;

  hipMemsetAsync(d_out, 0, sizeof(float), stream);
  hipMemsetAsync(C, 0, (size_t)B_ * R_ * M_ * sizeof(float), stream);

  k_extra_norms<<<(B_ * M_ + 3) / 4, 256, 0, stream>>>(teacher, invn);
  k_shnorm<<<(2 * B_ * 3 * NS_ + 3) / 4, 256, 0, stream>>>(teacher, student,
                                                           shared_perm, nsh);
  k_ref_gather<<<B_ * R_, 256, 0, stream>>>(teacher, student, ref_perm,
                                            reft, refs, prrt, prrs);
  k_sim_gemm<<<688, 256, 0, stream>>>(teacher, reft, C);
  k_topk<<<B_ * R_, 256, 0, stream>>>(C, invn, idx);
  k_prep<<<B_ * R_, 256, 0, stream>>>(teacher, reft, refs, idx,
                                      prst, prss, pss, ib1t, ib1s);
  k_loss<<<dim3(B_ * R_, 3, 2), 256, 0, stream>>>(teacher, student, shared_perm, idx,
                                                  reft, refs, prrt, prrs,
                                                  prst, prss, pss, ib1t, ib1s,
                                                  nsh, (float*)d_out);
}

// Round 10
// 320.524 us; speedup vs baseline: 1.6498x; 1.0706x over previous
//
#include <hip/hip_runtime.h>
#include <float.h>

// Problem constants
#define B_  2
#define ST_ 8      // teacher frames
#define SS_ 4      // student frames
#define P_  1369
#define D_  1024
#define R_  128
#define NS_ 128
#define K_  4
#define M_  5476   // 4 * P_ (extra frames 1,3,5,7 flattened)

// Workspace layout (float offsets). Total ~6.15M floats (~24.6 MB).
#define OFF_INVN  0u
#define OFF_REFT  11008u
#define OFF_REFS  (OFF_REFT + 262144u)
#define OFF_PRRT  (OFF_REFS + 262144u)
#define OFF_PRRS  (OFF_PRRT + 256u)
#define OFF_IDX   (OFF_PRRS + 256u)
#define OFF_PRST  (OFF_IDX + 1024u)
#define OFF_PRSS  (OFF_PRST + 1024u)
#define OFF_PSS   (OFF_PRSS + 1024u)
#define OFF_IB1T  (OFF_PSS + 1024u)
#define OFF_IB1S  (OFF_IB1T + 1024u)
#define OFF_NSH   (OFF_IB1S + 1024u)   // 1536 floats
#define OFF_C     (OFF_NSH + 1536u)    // 4 partial buffers, each CP_ floats
#define CP_       1401856u             // B_*R_*M_

__device__ __forceinline__ float dot4(const float4 a, const float4 b) {
  return a.x*b.x + a.y*b.y + a.z*b.z + a.w*b.w;
}

// ---------------------------------------------------------------------------
// K1: inverse norms of the 4 "extra" teacher frames' rows. One wave per row.
__global__ __launch_bounds__(256) void k_extra_norms(const float* __restrict__ teacher,
                                                     float* __restrict__ invn) {
  int row = blockIdx.x * 4 + (threadIdx.x >> 6);
  int lane = threadIdx.x & 63;
  if (row >= B_ * M_) return;
  int b = row / M_, m = row % M_;
  int j = m / P_, p = m % P_;                 // extra frame j -> teacher frame 1+2j
  const float* src = teacher + (((size_t)b * ST_ + 1 + 2 * j) * P_ + p) * D_;
  float s = 0.f;
  #pragma unroll
  for (int it = 0; it < 4; ++it) {
    float4 v = *(const float4*)(src + (it * 64 + lane) * 4);
    s += dot4(v, v);
  }
  for (int o = 32; o; o >>= 1) s += __shfl_down(s, o);
  if (lane == 0) invn[row] = 1.f / fmaxf(sqrtf(s), 1e-12f);
}

// ---------------------------------------------------------------------------
// K1c: squared norms of the shared rows used by k_loss. 1536 rows, one wave each.
__global__ __launch_bounds__(256) void k_shnorm(const float* __restrict__ teacher,
                                                const float* __restrict__ student,
                                                const int* __restrict__ shared_perm,
                                                float* __restrict__ nsh) {
  int row = blockIdx.x * 4 + (threadIdx.x >> 6);
  int lane = threadIdx.x & 63;
  if (row >= 2 * B_ * 3 * NS_) return;
  int rid = row % (B_ * 3 * NS_);
  int is_stu = row / (B_ * 3 * NS_);
  int b = rid / (3 * NS_);
  int rem = rid % (3 * NS_);
  int f = rem / NS_, s = rem % NS_;
  int p = shared_perm[s];
  const float* src = is_stu
      ? student + (((size_t)b * SS_ + 1 + f) * P_ + p) * D_
      : teacher + (((size_t)b * ST_ + 2 + 2 * f) * P_ + p) * D_;
  float acc = 0.f;
  #pragma unroll
  for (int it = 0; it < 4; ++it) {
    float4 v = *(const float4*)(src + (it * 64 + lane) * 4);
    acc += dot4(v, v);
  }
  for (int o = 32; o; o >>= 1) acc += __shfl_down(acc, o);
  if (lane == 0) nsh[row] = acc;
}

// ---------------------------------------------------------------------------
// K1b: gather ref_t / ref_s rows (frame 0, ref_perm) and their squared norms.
__global__ __launch_bounds__(256) void k_ref_gather(const float* __restrict__ teacher,
                                                    const float* __restrict__ student,
                                                    const int* __restrict__ ref_perm,
                                                    float* __restrict__ reft,
                                                    float* __restrict__ refs,
                                                    float* __restrict__ prrt,
                                                    float* __restrict__ prrs) {
  int br = blockIdx.x;          // b*R + r
  int b = br / R_, r = br % R_;
  int p = ref_perm[r];
  const float* st = teacher + (((size_t)b * ST_ + 0) * P_ + p) * D_;
  const float* ss = student + (((size_t)b * SS_ + 0) * P_ + p) * D_;
  float* dt = reft + (size_t)br * D_;
  float* dsp = refs + (size_t)br * D_;
  int t = threadIdx.x;
  float4 vt = *(const float4*)(st + t * 4);
  float4 vs = *(const float4*)(ss + t * 4);
  *(float4*)(dt + t * 4) = vt;
  *(float4*)(dsp + t * 4) = vs;
  float at = dot4(vt, vt);
  float as = dot4(vs, vs);
  for (int o = 32; o; o >>= 1) { at += __shfl_down(at, o); as += __shfl_down(as, o); }
  __shared__ float red[16];
  int w = t >> 6, lane = t & 63;
  if (lane == 0) { red[w] = at; red[8 + w] = as; }
  __syncthreads();
  if (t == 0) {
    prrt[br] = red[0] + red[1] + red[2] + red[3];
    prrs[br] = red[8] + red[9] + red[10] + red[11];
  }
}

// ---------------------------------------------------------------------------
// K2 v3: split-K x4 into 4 SEPARATE partial buffers (plain stores, no atomics,
// no memset). 1376 blocks (5.4/CU). Cp[kq][br][m] = sum over K quarter kq.
__global__ __launch_bounds__(256) void k_sim_gemm(const float* __restrict__ teacher,
                                                  const float* __restrict__ reft,
                                                  float* __restrict__ Cp) {
  const int bid = blockIdx.x;            // 2(b) * 2(rt) * 86(mt) * 4(kq) = 1376
  const int kq  = bid & 3;
  const int rest = bid >> 2;
  const int b   = rest / 172;
  const int rem = rest % 172;
  const int rt  = rem / 86;
  const int mt  = rem % 86;
  const int r0 = rt * 64, m0 = mt * 64;
  __shared__ __align__(16) float Al[32 * 68];   // [kk][r], stride 68
  __shared__ __align__(16) float El[32 * 68];
  const int t = threadIdx.x;
  const int tx = t & 15, ty = t >> 4;
  const int lr = t >> 3;                 // 0..31
  const int lk = (t & 7) * 4;            // 0,4,...,28
  const float* arow0 = reft + (size_t)(b * R_ + r0 + lr) * D_;
  const float* arow1 = reft + (size_t)(b * R_ + r0 + 32 + lr) * D_;
  const float* erow0; const float* erow1; bool ev0, ev1;
  {
    int m = m0 + lr; ev0 = m < M_;
    int mm = ev0 ? m : 0; int j = mm / P_, p = mm % P_;
    erow0 = teacher + (((size_t)b * ST_ + 1 + 2 * j) * P_ + p) * D_;
    m = m0 + 32 + lr; ev1 = m < M_;
    mm = ev1 ? m : 0; j = mm / P_; p = mm % P_;
    erow1 = teacher + (((size_t)b * ST_ + 1 + 2 * j) * P_ + p) * D_;
  }
  float acc[4][4];
  #pragma unroll
  for (int i = 0; i < 4; ++i)
    #pragma unroll
    for (int j = 0; j < 4; ++j) acc[i][j] = 0.f;

  const int kbeg = kq * 256, kend = kbeg + 256;
  for (int kc = kbeg; kc < kend; kc += 32) {
    __syncthreads();
    float4 a0 = *(const float4*)(arow0 + kc + lk);
    float4 a1 = *(const float4*)(arow1 + kc + lk);
    float4 e0 = ev0 ? *(const float4*)(erow0 + kc + lk) : make_float4(0, 0, 0, 0);
    float4 e1 = ev1 ? *(const float4*)(erow1 + kc + lk) : make_float4(0, 0, 0, 0);
    Al[(lk + 0) * 68 + lr] = a0.x; Al[(lk + 1) * 68 + lr] = a0.y;
    Al[(lk + 2) * 68 + lr] = a0.z; Al[(lk + 3) * 68 + lr] = a0.w;
    Al[(lk + 0) * 68 + 32 + lr] = a1.x; Al[(lk + 1) * 68 + 32 + lr] = a1.y;
    Al[(lk + 2) * 68 + 32 + lr] = a1.z; Al[(lk + 3) * 68 + 32 + lr] = a1.w;
    El[(lk + 0) * 68 + lr] = e0.x; El[(lk + 1) * 68 + lr] = e0.y;
    El[(lk + 2) * 68 + lr] = e0.z; El[(lk + 3) * 68 + lr] = e0.w;
    El[(lk + 0) * 68 + 32 + lr] = e1.x; El[(lk + 1) * 68 + 32 + lr] = e1.y;
    El[(lk + 2) * 68 + 32 + lr] = e1.z; El[(lk + 3) * 68 + 32 + lr] = e1.w;
    __syncthreads();
    #pragma unroll
    for (int kk = 0; kk < 32; ++kk) {
      float4 av = *(const float4*)&Al[kk * 68 + ty * 4];
      float4 ev = *(const float4*)&El[kk * 68 + tx * 4];
      acc[0][0] += av.x * ev.x; acc[0][1] += av.x * ev.y; acc[0][2] += av.x * ev.z; acc[0][3] += av.x * ev.w;
      acc[1][0] += av.y * ev.x; acc[1][1] += av.y * ev.y; acc[1][2] += av.y * ev.z; acc[1][3] += av.y * ev.w;
      acc[2][0] += av.z * ev.x; acc[2][1] += av.z * ev.y; acc[2][2] += av.z * ev.z; acc[2][3] += av.z * ev.w;
      acc[3][0] += av.w * ev.x; acc[3][1] += av.w * ev.y; acc[3][2] += av.w * ev.z; acc[3][3] += av.w * ev.w;
    }
  }
  const int mbase = m0 + tx * 4;
  float* cbase = Cp + (size_t)kq * CP_;
  #pragma unroll
  for (int i = 0; i < 4; ++i) {
    int r = r0 + ty * 4 + i;
    float* crow = cbase + (size_t)(b * R_ + r) * M_;
    if (mbase + 3 < M_) {
      *(float4*)(crow + mbase) = make_float4(acc[i][0], acc[i][1], acc[i][2], acc[i][3]);
    } else {
      if (mbase + 0 < M_) crow[mbase + 0] = acc[i][0];
      if (mbase + 1 < M_) crow[mbase + 1] = acc[i][1];
      if (mbase + 2 < M_) crow[mbase + 2] = acc[i][2];
      if (mbase + 3 < M_) crow[mbase + 3] = acc[i][3];
    }
  }
}

// ---------------------------------------------------------------------------
// K3: top-4 per (b,r) row: sum the 4 K-partials (fixed order -> deterministic),
// scale by invn[m] (positive), select. (value desc, index asc) = lax.top_k rule.
__device__ __forceinline__ void topk_insert(float v, int m, float bv[4], int bi[4]) {
  bool better3 = (v > bv[3]) || (v == bv[3] && m < bi[3]);
  if (!better3) return;
  int pos = 3;
  while (pos > 0) {
    bool better = (v > bv[pos - 1]) || (v == bv[pos - 1] && m < bi[pos - 1]);
    if (better) { bv[pos] = bv[pos - 1]; bi[pos] = bi[pos - 1]; --pos; }
    else break;
  }
  bv[pos] = v; bi[pos] = m;
}

__global__ __launch_bounds__(256) void k_topk(const float* __restrict__ Cp,
                                              const float* __restrict__ invn,
                                              int* __restrict__ idxout) {
  int br = blockIdx.x;
  int b = br / R_;
  const float* r0 = Cp + 0 * (size_t)CP_ + (size_t)br * M_;
  const float* r1 = Cp + 1 * (size_t)CP_ + (size_t)br * M_;
  const float* r2 = Cp + 2 * (size_t)CP_ + (size_t)br * M_;
  const float* r3 = Cp + 3 * (size_t)CP_ + (size_t)br * M_;
  const float* w = invn + (size_t)b * M_;
  int t = threadIdx.x;
  float bv[4] = {-FLT_MAX, -FLT_MAX, -FLT_MAX, -FLT_MAX};
  int   bi[4] = {0x7fffffff, 0x7fffffff, 0x7fffffff, 0x7fffffff};
  for (int m = t; m < M_; m += 256) {
    float v = ((r0[m] + r1[m]) + (r2[m] + r3[m])) * w[m];
    topk_insert(v, m, bv, bi);
  }

  // wave-level butterfly merge: all 64 lanes converge to the wave's top-4
  #pragma unroll
  for (int o = 1; o < 64; o <<= 1) {
    float ov[4]; int oi[4];
    #pragma unroll
    for (int q = 0; q < 4; ++q) {
      ov[q] = __shfl_xor(bv[q], o);
      oi[q] = __shfl_xor(bi[q], o);
    }
    #pragma unroll
    for (int q = 0; q < 4; ++q) topk_insert(ov[q], oi[q], bv, bi);
  }

  __shared__ float sv[16];
  __shared__ int   si[16];
  int wv = t >> 6, lane = t & 63;
  if (lane == 0) {
    #pragma unroll
    for (int q = 0; q < 4; ++q) { sv[wv * 4 + q] = bv[q]; si[wv * 4 + q] = bi[q]; }
  }
  __syncthreads();
  if (t == 0) {
    float tv[4] = {-FLT_MAX, -FLT_MAX, -FLT_MAX, -FLT_MAX};
    int   ti[4] = {0x7fffffff, 0x7fffffff, 0x7fffffff, 0x7fffffff};
    #pragma unroll
    for (int e = 0; e < 16; ++e) topk_insert(sv[e], si[e], tv, ti);
    #pragma unroll
    for (int q = 0; q < 4; ++q) idxout[br * 4 + q] = ti[q];
  }
}

// ---------------------------------------------------------------------------
// K4: per (b,r,k) scalars: ||sim||^2, ref_t.sim, ref_s.sim, 1/max(||sim-ref_x||,eps)
__global__ __launch_bounds__(256) void k_prep(const float* __restrict__ teacher,
                                              const float* __restrict__ reft,
                                              const float* __restrict__ refs,
                                              const int* __restrict__ idx,
                                              float* __restrict__ prst,
                                              float* __restrict__ prss,
                                              float* __restrict__ pss,
                                              float* __restrict__ ib1t,
                                              float* __restrict__ ib1s) {
  int br = blockIdx.x;
  int b = br / R_;
  int w = threadIdx.x >> 6, lane = threadIdx.x & 63;
  int m = idx[br * 4 + w];
  int j = m / P_, p = m % P_;
  const float* sim = teacher + (((size_t)b * ST_ + 1 + 2 * j) * P_ + p) * D_;
  const float* rt = reft + (size_t)br * D_;
  const float* rs = refs + (size_t)br * D_;
  float s_ss = 0, s_rt = 0, s_rs = 0, s_dt = 0, s_ds = 0;
  #pragma unroll
  for (int it = 0; it < 4; ++it) {
    int d = (it * 64 + lane) * 4;
    float4 svv = *(const float4*)(sim + d);
    float4 tvv = *(const float4*)(rt + d);
    float4 uvv = *(const float4*)(rs + d);
    s_ss += dot4(svv, svv);
    s_rt += dot4(svv, tvv);
    s_rs += dot4(svv, uvv);
    float4 dt = make_float4(svv.x - tvv.x, svv.y - tvv.y, svv.z - tvv.z, svv.w - tvv.w);
    float4 ds = make_float4(svv.x - uvv.x, svv.y - uvv.y, svv.z - uvv.z, svv.w - uvv.w);
    s_dt += dot4(dt, dt);
    s_ds += dot4(ds, ds);
  }
  for (int o = 32; o; o >>= 1) {
    s_ss += __shfl_down(s_ss, o); s_rt += __shfl_down(s_rt, o); s_rs += __shfl_down(s_rs, o);
    s_dt += __shfl_down(s_dt, o); s_ds += __shfl_down(s_ds, o);
  }
  if (lane == 0) {
    int o = br * 4 + w;
    pss[o] = s_ss; prst[o] = s_rt; prss[o] = s_rs;
    ib1t[o] = 1.f / fmaxf(sqrtf(s_dt), 1e-8f);
    ib1s[o] = 1.f / fmaxf(sqrtf(s_ds), 1e-8f);
  }
}

// ---------------------------------------------------------------------------
// K5 v2: fused loss. Block = (br, frame, s-chunk of 64). 64 groups of 4 lanes;
// each group owns one s, each lane one k. 2-level reduce.
__device__ __forceinline__ float huber1(float d) {
  float ad = fabsf(d);
  return (ad < 1.0f) ? 0.5f * d * d : (ad - 0.5f);
}

__global__ __launch_bounds__(256) void k_loss(const float* __restrict__ teacher,
                                              const float* __restrict__ student,
                                              const int* __restrict__ shared_perm,
                                              const int* __restrict__ idx,
                                              const float* __restrict__ reft,
                                              const float* __restrict__ refs,
                                              const float* __restrict__ prrt,
                                              const float* __restrict__ prrs,
                                              const float* __restrict__ prst,
                                              const float* __restrict__ prss,
                                              const float* __restrict__ pss,
                                              const float* __restrict__ ib1t,
                                              const float* __restrict__ ib1s,
                                              const float* __restrict__ nsh,
                                              float* __restrict__ out) {
  int br = blockIdx.x, f = blockIdx.y, sc = blockIdx.z;
  int b = br / R_;
  int tf = 2 + 2 * f;   // teacher frames 2,4,6
  int sf = 1 + f;       // student frames 1,2,3
  __shared__ __align__(16) float Lsim[4][1024];
  __shared__ __align__(16) float Lrt[1024];
  __shared__ __align__(16) float Lrs[1024];
  __shared__ int sperm[128];
  __shared__ float Lns[2][64];
  __shared__ float scal[22];
  __shared__ float wred[4];
  int t = threadIdx.x;
  {
    const float* rt = reft + (size_t)br * D_;
    const float* rs = refs + (size_t)br * D_;
    *(float4*)&Lrt[t * 4] = *(const float4*)(rt + t * 4);
    *(float4*)&Lrs[t * 4] = *(const float4*)(rs + t * 4);
    #pragma unroll
    for (int k = 0; k < 4; ++k) {
      int m = idx[br * 4 + k]; int j = m / P_, p = m % P_;
      const float* sim = teacher + (((size_t)b * ST_ + 1 + 2 * j) * P_ + p) * D_;
      *(float4*)&Lsim[k][t * 4] = *(const float4*)(sim + t * 4);
    }
  }
  if (t < 128) sperm[t] = shared_perm[t];
  if (t < 64) {
    int o = (b * 3 + f) * NS_ + sc * 64 + t;
    Lns[0][t] = nsh[o];
    Lns[1][t] = nsh[B_ * 3 * NS_ + o];
  }
  if (t < 4) {
    int o = br * 4 + t;
    scal[t] = prst[o]; scal[4 + t] = prss[o]; scal[8 + t] = pss[o];
    scal[12 + t] = ib1t[o]; scal[16 + t] = ib1s[o];
  }
  if (t == 4) scal[20] = prrt[br];
  if (t == 5) scal[21] = prrs[br];
  __syncthreads();

  const int g = t >> 2, gl = t & 3;
  const int s = sc * 64 + g;
  const int p = sperm[s];
  const float* sht = teacher + (((size_t)b * ST_ + tf) * P_ + p) * D_;
  const float* shs = student + (((size_t)b * SS_ + sf) * P_ + p) * D_;

  float qt0 = 0, qt1 = 0, qt2 = 0, qt3 = 0, qtr = 0;
  float qs0 = 0, qs1 = 0, qs2 = 0, qs3 = 0, qsr = 0;
  #pragma unroll 2
  for (int i = 0; i < 64; ++i) {
    int off = i * 16 + gl * 4;
    float4 a  = *(const float4*)(sht + off);
    float4 c  = *(const float4*)(shs + off);
    float4 v0 = *(const float4*)&Lsim[0][off];
    float4 v1 = *(const float4*)&Lsim[1][off];
    float4 v2 = *(const float4*)&Lsim[2][off];
    float4 v3 = *(const float4*)&Lsim[3][off];
    float4 r1 = *(const float4*)&Lrt[off];
    float4 r2 = *(const float4*)&Lrs[off];
    qt0 += dot4(a, v0); qt1 += dot4(a, v1); qt2 += dot4(a, v2); qt3 += dot4(a, v3);
    qtr += dot4(a, r1);
    qs0 += dot4(c, v0); qs1 += dot4(c, v1); qs2 += dot4(c, v2); qs3 += dot4(c, v3);
    qsr += dot4(c, r2);
  }
  // 2-level butterfly within the 4-lane group
  #pragma unroll
  for (int o = 1; o <= 2; o <<= 1) {
    qt0 += __shfl_xor(qt0, o); qt1 += __shfl_xor(qt1, o);
    qt2 += __shfl_xor(qt2, o); qt3 += __shfl_xor(qt3, o);
    qtr += __shfl_xor(qtr, o);
    qs0 += __shfl_xor(qs0, o); qs1 += __shfl_xor(qs1, o);
    qs2 += __shfl_xor(qs2, o); qs3 += __shfl_xor(qs3, o);
    qsr += __shfl_xor(qsr, o);
  }
  // lane gl handles k = gl (static selects, no scratch)
  const int k = gl;
  float qsim  = (gl == 0) ? qt0 : (gl == 1) ? qt1 : (gl == 2) ? qt2 : qt3;
  float qsimS = (gl == 0) ? qs0 : (gl == 1) ? qs1 : (gl == 2) ? qs2 : qs3;
  float qref = qtr, qrefS = qsr;
  float qss = Lns[0][g], qssS = Lns[1][g];

  float Prs_t = scal[k], Prs_s = scal[4 + k], Pss_k = scal[8 + k];
  float ibt = scal[12 + k], ibs = scal[16 + k];
  float Prr_t = scal[20], Prr_s = scal[21];
  // teacher
  float n1sq = qss - 2.f * qref + Prr_t;
  float i1 = 1.f / fmaxf(sqrtf(fmaxf(n1sq, 0.f)), 1e-8f);
  float n2sq = qss - 2.f * qsim + Pss_k;
  float i2 = 1.f / fmaxf(sqrtf(fmaxf(n2sq, 0.f)), 1e-8f);
  float a1t = (qsim - qref - Prs_t + Prr_t) * ibt * i1;
  float a2t = -(qsim - Pss_k - qref + Prs_t) * ibt * i2;
  float a3t = (qss - qsim - qref + Prs_t) * i1 * i2;
  // student
  float n1sqS = qssS - 2.f * qrefS + Prr_s;
  float i1s = 1.f / fmaxf(sqrtf(fmaxf(n1sqS, 0.f)), 1e-8f);
  float n2sqS = qssS - 2.f * qsimS + Pss_k;
  float i2s = 1.f / fmaxf(sqrtf(fmaxf(n2sqS, 0.f)), 1e-8f);
  float a1s = (qsimS - qrefS - Prs_s + Prr_s) * ibs * i1s;
  float a2s = -(qsimS - Pss_k - qrefS + Prs_s) * ibs * i2s;
  float a3s = (qssS - qsimS - qrefS + Prs_s) * i1s * i2s;
  float lacc = huber1(a1s - a1t) + huber1(a2s - a2t) + huber1(a3s - a3t);

  // block reduction
  int w = t >> 6, lane = t & 63;
  for (int o = 32; o; o >>= 1) lacc += __shfl_down(lacc, o);
  if (lane == 0) wred[w] = lacc;
  __syncthreads();
  if (t == 0) {
    float ssum = wred[0] + wred[1] + wred[2] + wred[3];
    atomicAdd(out, ssum * (1.0f / 393216.0f));  // /= B*R*NS*K*3 (W1=W2=W3=1)
  }
}

// ---------------------------------------------------------------------------
extern "C" void kernel_launch(void* const* d_in, const int* in_sizes, int n_in,
                              void* d_out, int out_size, void* d_ws, size_t ws_size,
                              hipStream_t stream) {
  const float* teacher = (const float*)d_in[0];
  const float* student = (const float*)d_in[1];
  const int* ref_perm = (const int*)d_in[2];
  const int* shared_perm = (const int*)d_in[3];
  float* ws = (float*)d_ws;
  float* invn = ws + OFF_INVN;
  float* reft = ws + OFF_REFT;
  float* refs = ws + OFF_REFS;
  float* prrt = ws + OFF_PRRT;
  float* prrs = ws + OFF_PRRS;
  int*   idx  = (int*)(ws + OFF_IDX);
  float* prst = ws + OFF_PRST;
  float* prss = ws + OFF_PRSS;
  float* pss  = ws + OFF_PSS;
  float* ib1t = ws + OFF_IB1T;
  float* ib1s = ws + OFF_IB1S;
  float* nsh  = ws + OFF_NSH;
  float* Cp   = ws + OFF_C;

  hipMemsetAsync(d_out, 0, sizeof(float), stream);

  k_extra_norms<<<(B_ * M_ + 3) / 4, 256, 0, stream>>>(teacher, invn);
  k_shnorm<<<(2 * B_ * 3 * NS_ + 3) / 4, 256, 0, stream>>>(teacher, student,
                                                           shared_perm, nsh);
  k_ref_gather<<<B_ * R_, 256, 0, stream>>>(teacher, student, ref_perm,
                                            reft, refs, prrt, prrs);
  k_sim_gemm<<<1376, 256, 0, stream>>>(teacher, reft, Cp);
  k_topk<<<B_ * R_, 256, 0, stream>>>(Cp, invn, idx);
  k_prep<<<B_ * R_, 256, 0, stream>>>(teacher, reft, refs, idx,
                                      prst, prss, pss, ib1t, ib1s);
  k_loss<<<dim3(B_ * R_, 3, 2), 256, 0, stream>>>(teacher, student, shared_perm, idx,
                                                  reft, refs, prrt, prrs,
                                                  prst, prss, pss, ib1t, ib1s,
                                                  nsh, (float*)d_out);
}

// Round 11
// 305.358 us; speedup vs baseline: 1.7318x; 1.0497x over previous
//
#include <hip/hip_runtime.h>
#include <float.h>

// Problem constants
#define B_  2
#define ST_ 8      // teacher frames
#define SS_ 4      // student frames
#define P_  1369
#define D_  1024
#define R_  128
#define NS_ 128
#define K_  4
#define M_  5476   // 4 * P_ (extra frames 1,3,5,7 flattened)

// Workspace layout (float offsets). Total ~6.16M floats (~24.7 MB) - R10 proved OK.
#define OFF_INVN  0u
#define OFF_REFT  11008u
#define OFF_REFS  (OFF_REFT + 262144u)
#define OFF_PRRT  (OFF_REFS + 262144u)
#define OFF_PRRS  (OFF_PRRT + 256u)
#define OFF_IDX   (OFF_PRRS + 256u)
#define OFF_PRST  (OFF_IDX + 1024u)
#define OFF_PRSS  (OFF_PRST + 1024u)
#define OFF_PSS   (OFF_PRSS + 1024u)
#define OFF_IB1T  (OFF_PSS + 1024u)
#define OFF_IB1S  (OFF_IB1T + 1024u)
#define OFF_NSH   (OFF_IB1S + 1024u)   // 1536 floats
#define OFF_CANDV (OFF_NSH + 1536u)    // 256 br x 16 candidate values
#define OFF_CANDI (OFF_CANDV + 4096u)  // 256 br x 16 candidate indices
#define OFF_C     (OFF_CANDI + 4096u)  // 4 partial buffers, each CP_ floats
#define CP_       1401856u             // B_*R_*M_

// fused-prep block ranges
#define NA_BLOCKS 2738   // ceil(B_*M_ / 4)  extra-norm rows
#define NB_BLOCKS 384    // 1536/4           shnorm rows
#define NC_BLOCKS 256    // B_*R_            ref_gather

__device__ __forceinline__ float dot4(const float4 a, const float4 b) {
  return a.x*b.x + a.y*b.y + a.z*b.z + a.w*b.w;
}

// ---------------------------------------------------------------------------
// K0: fused prep = extra-norms + shared-row norms + ref gather (independent
// jobs dispatched by blockIdx range; one launch instead of three).
__global__ __launch_bounds__(256) void k_prep0(const float* __restrict__ teacher,
                                               const float* __restrict__ student,
                                               const int* __restrict__ ref_perm,
                                               const int* __restrict__ shared_perm,
                                               float* __restrict__ invn,
                                               float* __restrict__ nsh,
                                               float* __restrict__ reft,
                                               float* __restrict__ refs,
                                               float* __restrict__ prrt,
                                               float* __restrict__ prrs) {
  const int bid = blockIdx.x;
  const int t = threadIdx.x;
  if (bid < NA_BLOCKS) {
    // extra-frame inverse norms, one wave per row
    int row = bid * 4 + (t >> 6);
    int lane = t & 63;
    if (row >= B_ * M_) return;
    int b = row / M_, m = row % M_;
    int j = m / P_, p = m % P_;
    const float* src = teacher + (((size_t)b * ST_ + 1 + 2 * j) * P_ + p) * D_;
    float s = 0.f;
    #pragma unroll
    for (int it = 0; it < 4; ++it) {
      float4 v = *(const float4*)(src + (it * 64 + lane) * 4);
      s += dot4(v, v);
    }
    for (int o = 32; o; o >>= 1) s += __shfl_down(s, o);
    if (lane == 0) invn[row] = 1.f / fmaxf(sqrtf(s), 1e-12f);
  } else if (bid < NA_BLOCKS + NB_BLOCKS) {
    // shared-row squared norms, one wave per row
    int row = (bid - NA_BLOCKS) * 4 + (t >> 6);
    int lane = t & 63;
    if (row >= 2 * B_ * 3 * NS_) return;
    int rid = row % (B_ * 3 * NS_);
    int is_stu = row / (B_ * 3 * NS_);
    int b = rid / (3 * NS_);
    int rem = rid % (3 * NS_);
    int f = rem / NS_, s = rem % NS_;
    int p = shared_perm[s];
    const float* src = is_stu
        ? student + (((size_t)b * SS_ + 1 + f) * P_ + p) * D_
        : teacher + (((size_t)b * ST_ + 2 + 2 * f) * P_ + p) * D_;
    float acc = 0.f;
    #pragma unroll
    for (int it = 0; it < 4; ++it) {
      float4 v = *(const float4*)(src + (it * 64 + lane) * 4);
      acc += dot4(v, v);
    }
    for (int o = 32; o; o >>= 1) acc += __shfl_down(acc, o);
    if (lane == 0) nsh[row] = acc;
  } else {
    // ref gather + squared norms, one block per br
    int br = bid - (NA_BLOCKS + NB_BLOCKS);
    int b = br / R_, r = br % R_;
    int p = ref_perm[r];
    const float* st = teacher + (((size_t)b * ST_ + 0) * P_ + p) * D_;
    const float* ss = student + (((size_t)b * SS_ + 0) * P_ + p) * D_;
    float* dt = reft + (size_t)br * D_;
    float* dsp = refs + (size_t)br * D_;
    float4 vt = *(const float4*)(st + t * 4);
    float4 vs = *(const float4*)(ss + t * 4);
    *(float4*)(dt + t * 4) = vt;
    *(float4*)(dsp + t * 4) = vs;
    float at = dot4(vt, vt);
    float as = dot4(vs, vs);
    for (int o = 32; o; o >>= 1) { at += __shfl_down(at, o); as += __shfl_down(as, o); }
    __shared__ float red[16];
    int w = t >> 6, lane = t & 63;
    if (lane == 0) { red[w] = at; red[8 + w] = as; }
    __syncthreads();
    if (t == 0) {
      prrt[br] = red[0] + red[1] + red[2] + red[3];
      prrs[br] = red[8] + red[9] + red[10] + red[11];
    }
  }
}

// ---------------------------------------------------------------------------
// K2: split-K x4 into 4 SEPARATE partial buffers (plain stores, no atomics).
// 1376 blocks. Cp[kq][br][m] = partial over K quarter kq.  (unchanged)
__global__ __launch_bounds__(256) void k_sim_gemm(const float* __restrict__ teacher,
                                                  const float* __restrict__ reft,
                                                  float* __restrict__ Cp) {
  const int bid = blockIdx.x;            // 2(b) * 2(rt) * 86(mt) * 4(kq) = 1376
  const int kq  = bid & 3;
  const int rest = bid >> 2;
  const int b   = rest / 172;
  const int rem = rest % 172;
  const int rt  = rem / 86;
  const int mt  = rem % 86;
  const int r0 = rt * 64, m0 = mt * 64;
  __shared__ __align__(16) float Al[32 * 68];
  __shared__ __align__(16) float El[32 * 68];
  const int t = threadIdx.x;
  const int tx = t & 15, ty = t >> 4;
  const int lr = t >> 3;
  const int lk = (t & 7) * 4;
  const float* arow0 = reft + (size_t)(b * R_ + r0 + lr) * D_;
  const float* arow1 = reft + (size_t)(b * R_ + r0 + 32 + lr) * D_;
  const float* erow0; const float* erow1; bool ev0, ev1;
  {
    int m = m0 + lr; ev0 = m < M_;
    int mm = ev0 ? m : 0; int j = mm / P_, p = mm % P_;
    erow0 = teacher + (((size_t)b * ST_ + 1 + 2 * j) * P_ + p) * D_;
    m = m0 + 32 + lr; ev1 = m < M_;
    mm = ev1 ? m : 0; j = mm / P_; p = mm % P_;
    erow1 = teacher + (((size_t)b * ST_ + 1 + 2 * j) * P_ + p) * D_;
  }
  float acc[4][4];
  #pragma unroll
  for (int i = 0; i < 4; ++i)
    #pragma unroll
    for (int j = 0; j < 4; ++j) acc[i][j] = 0.f;

  const int kbeg = kq * 256, kend = kbeg + 256;
  for (int kc = kbeg; kc < kend; kc += 32) {
    __syncthreads();
    float4 a0 = *(const float4*)(arow0 + kc + lk);
    float4 a1 = *(const float4*)(arow1 + kc + lk);
    float4 e0 = ev0 ? *(const float4*)(erow0 + kc + lk) : make_float4(0, 0, 0, 0);
    float4 e1 = ev1 ? *(const float4*)(erow1 + kc + lk) : make_float4(0, 0, 0, 0);
    Al[(lk + 0) * 68 + lr] = a0.x; Al[(lk + 1) * 68 + lr] = a0.y;
    Al[(lk + 2) * 68 + lr] = a0.z; Al[(lk + 3) * 68 + lr] = a0.w;
    Al[(lk + 0) * 68 + 32 + lr] = a1.x; Al[(lk + 1) * 68 + 32 + lr] = a1.y;
    Al[(lk + 2) * 68 + 32 + lr] = a1.z; Al[(lk + 3) * 68 + 32 + lr] = a1.w;
    El[(lk + 0) * 68 + lr] = e0.x; El[(lk + 1) * 68 + lr] = e0.y;
    El[(lk + 2) * 68 + lr] = e0.z; El[(lk + 3) * 68 + lr] = e0.w;
    El[(lk + 0) * 68 + 32 + lr] = e1.x; El[(lk + 1) * 68 + 32 + lr] = e1.y;
    El[(lk + 2) * 68 + 32 + lr] = e1.z; El[(lk + 3) * 68 + 32 + lr] = e1.w;
    __syncthreads();
    #pragma unroll
    for (int kk = 0; kk < 32; ++kk) {
      float4 av = *(const float4*)&Al[kk * 68 + ty * 4];
      float4 ev = *(const float4*)&El[kk * 68 + tx * 4];
      acc[0][0] += av.x * ev.x; acc[0][1] += av.x * ev.y; acc[0][2] += av.x * ev.z; acc[0][3] += av.x * ev.w;
      acc[1][0] += av.y * ev.x; acc[1][1] += av.y * ev.y; acc[1][2] += av.y * ev.z; acc[1][3] += av.y * ev.w;
      acc[2][0] += av.z * ev.x; acc[2][1] += av.z * ev.y; acc[2][2] += av.z * ev.z; acc[2][3] += av.z * ev.w;
      acc[3][0] += av.w * ev.x; acc[3][1] += av.w * ev.y; acc[3][2] += av.w * ev.z; acc[3][3] += av.w * ev.w;
    }
  }
  const int mbase = m0 + tx * 4;
  float* cbase = Cp + (size_t)kq * CP_;
  #pragma unroll
  for (int i = 0; i < 4; ++i) {
    int r = r0 + ty * 4 + i;
    float* crow = cbase + (size_t)(b * R_ + r) * M_;
    if (mbase + 3 < M_) {
      *(float4*)(crow + mbase) = make_float4(acc[i][0], acc[i][1], acc[i][2], acc[i][3]);
    } else {
      if (mbase + 0 < M_) crow[mbase + 0] = acc[i][0];
      if (mbase + 1 < M_) crow[mbase + 1] = acc[i][1];
      if (mbase + 2 < M_) crow[mbase + 2] = acc[i][2];
      if (mbase + 3 < M_) crow[mbase + 3] = acc[i][3];
    }
  }
}

// ---------------------------------------------------------------------------
// Top-k helpers: (value desc, index asc) total order = lax.top_k rule.
__device__ __forceinline__ void topk_insert(float v, int m, float bv[4], int bi[4]) {
  bool better3 = (v > bv[3]) || (v == bv[3] && m < bi[3]);
  if (!better3) return;
  int pos = 3;
  while (pos > 0) {
    bool better = (v > bv[pos - 1]) || (v == bv[pos - 1] && m < bi[pos - 1]);
    if (better) { bv[pos] = bv[pos - 1]; bi[pos] = bi[pos - 1]; --pos; }
    else break;
  }
  bv[pos] = v; bi[pos] = m;
}

// K3a: stage-1 top-4 per (br, chunk of M/4). 1024 blocks (4/CU vs old 1/CU).
// Chunks are disjoint, so stage-2 merge of chunk winners is exact.
__global__ __launch_bounds__(256) void k_topk1(const float* __restrict__ Cp,
                                               const float* __restrict__ invn,
                                               float* __restrict__ candv,
                                               int* __restrict__ candi) {
  int bid = blockIdx.x;            // br*4 + q
  int br = bid >> 2, q = bid & 3;
  int b = br / R_;
  const float* r0 = Cp + 0 * (size_t)CP_ + (size_t)br * M_;
  const float* r1 = Cp + 1 * (size_t)CP_ + (size_t)br * M_;
  const float* r2 = Cp + 2 * (size_t)CP_ + (size_t)br * M_;
  const float* r3 = Cp + 3 * (size_t)CP_ + (size_t)br * M_;
  const float* w = invn + (size_t)b * M_;
  const int mbeg = q * 1369, mend = mbeg + 1369;
  int t = threadIdx.x;
  float bv[4] = {-FLT_MAX, -FLT_MAX, -FLT_MAX, -FLT_MAX};
  int   bi[4] = {0x7fffffff, 0x7fffffff, 0x7fffffff, 0x7fffffff};
  for (int m = mbeg + t; m < mend; m += 256) {
    float v = ((r0[m] + r1[m]) + (r2[m] + r3[m])) * w[m];
    topk_insert(v, m, bv, bi);
  }
  #pragma unroll
  for (int o = 1; o < 64; o <<= 1) {
    float ov[4]; int oi[4];
    #pragma unroll
    for (int qq = 0; qq < 4; ++qq) {
      ov[qq] = __shfl_xor(bv[qq], o);
      oi[qq] = __shfl_xor(bi[qq], o);
    }
    #pragma unroll
    for (int qq = 0; qq < 4; ++qq) topk_insert(ov[qq], oi[qq], bv, bi);
  }
  __shared__ float sv[16];
  __shared__ int   si[16];
  int wv = t >> 6, lane = t & 63;
  if (lane == 0) {
    #pragma unroll
    for (int qq = 0; qq < 4; ++qq) { sv[wv * 4 + qq] = bv[qq]; si[wv * 4 + qq] = bi[qq]; }
  }
  __syncthreads();
  if (t == 0) {
    float tv[4] = {-FLT_MAX, -FLT_MAX, -FLT_MAX, -FLT_MAX};
    int   ti[4] = {0x7fffffff, 0x7fffffff, 0x7fffffff, 0x7fffffff};
    #pragma unroll
    for (int e = 0; e < 16; ++e) topk_insert(sv[e], si[e], tv, ti);
    #pragma unroll
    for (int qq = 0; qq < 4; ++qq) { candv[bid * 4 + qq] = tv[qq]; candi[bid * 4 + qq] = ti[qq]; }
  }
}

// ---------------------------------------------------------------------------
// K4: stage-2 merge (wave 0, shfl butterfly over 16 candidates) + per (br,k)
// scalars: ||sim||^2, ref_t.sim, ref_s.sim, 1/max(||sim-ref_x||,eps).
__global__ __launch_bounds__(256) void k_prep(const float* __restrict__ teacher,
                                              const float* __restrict__ reft,
                                              const float* __restrict__ refs,
                                              const float* __restrict__ candv,
                                              const int* __restrict__ candi,
                                              int* __restrict__ idxout,
                                              float* __restrict__ prst,
                                              float* __restrict__ prss,
                                              float* __restrict__ pss,
                                              float* __restrict__ ib1t,
                                              float* __restrict__ ib1s) {
  int br = blockIdx.x;
  int b = br / R_;
  int t = threadIdx.x;
  __shared__ int sidx[4];
  if (t < 64) {
    float v = -FLT_MAX; int ix = 0x7fffffff;
    if (t < 16) { v = candv[br * 16 + t]; ix = candi[br * 16 + t]; }
    float bv[4] = {v, -FLT_MAX, -FLT_MAX, -FLT_MAX};
    int   bi[4] = {ix, 0x7fffffff, 0x7fffffff, 0x7fffffff};
    #pragma unroll
    for (int o = 1; o <= 8; o <<= 1) {
      float ov[4]; int oi[4];
      #pragma unroll
      for (int q = 0; q < 4; ++q) {
        ov[q] = __shfl_xor(bv[q], o);
        oi[q] = __shfl_xor(bi[q], o);
      }
      #pragma unroll
      for (int q = 0; q < 4; ++q) topk_insert(ov[q], oi[q], bv, bi);
    }
    if (t == 0) {
      #pragma unroll
      for (int q = 0; q < 4; ++q) { sidx[q] = bi[q]; idxout[br * 4 + q] = bi[q]; }
    }
  }
  __syncthreads();
  int w = t >> 6, lane = t & 63;
  int m = sidx[w];
  int j = m / P_, p = m % P_;
  const float* sim = teacher + (((size_t)b * ST_ + 1 + 2 * j) * P_ + p) * D_;
  const float* rt = reft + (size_t)br * D_;
  const float* rs = refs + (size_t)br * D_;
  float s_ss = 0, s_rt = 0, s_rs = 0, s_dt = 0, s_ds = 0;
  #pragma unroll
  for (int it = 0; it < 4; ++it) {
    int d = (it * 64 + lane) * 4;
    float4 svv = *(const float4*)(sim + d);
    float4 tvv = *(const float4*)(rt + d);
    float4 uvv = *(const float4*)(rs + d);
    s_ss += dot4(svv, svv);
    s_rt += dot4(svv, tvv);
    s_rs += dot4(svv, uvv);
    float4 dt = make_float4(svv.x - tvv.x, svv.y - tvv.y, svv.z - tvv.z, svv.w - tvv.w);
    float4 ds = make_float4(svv.x - uvv.x, svv.y - uvv.y, svv.z - uvv.z, svv.w - uvv.w);
    s_dt += dot4(dt, dt);
    s_ds += dot4(ds, ds);
  }
  for (int o = 32; o; o >>= 1) {
    s_ss += __shfl_down(s_ss, o); s_rt += __shfl_down(s_rt, o); s_rs += __shfl_down(s_rs, o);
    s_dt += __shfl_down(s_dt, o); s_ds += __shfl_down(s_ds, o);
  }
  if (lane == 0) {
    int o = br * 4 + w;
    pss[o] = s_ss; prst[o] = s_rt; prss[o] = s_rs;
    ib1t[o] = 1.f / fmaxf(sqrtf(s_dt), 1e-8f);
    ib1s[o] = 1.f / fmaxf(sqrtf(s_ds), 1e-8f);
  }
}

// ---------------------------------------------------------------------------
// K5 v3: fused loss. Block = (br, frame); 64 groups of 4 lanes, each group
// owns TWO s rows (s=g, s=g+64) -> 6 LDS reads feed 20 dot4s instead of 10
// (VALU:LDS 160:72 cyc vs 80:72 -> LDS off the critical path).
__device__ __forceinline__ float huber1(float d) {
  float ad = fabsf(d);
  return (ad < 1.0f) ? 0.5f * d * d : (ad - 0.5f);
}

__global__ __launch_bounds__(256) void k_loss(const float* __restrict__ teacher,
                                              const float* __restrict__ student,
                                              const int* __restrict__ shared_perm,
                                              const int* __restrict__ idx,
                                              const float* __restrict__ reft,
                                              const float* __restrict__ refs,
                                              const float* __restrict__ prrt,
                                              const float* __restrict__ prrs,
                                              const float* __restrict__ prst,
                                              const float* __restrict__ prss,
                                              const float* __restrict__ pss,
                                              const float* __restrict__ ib1t,
                                              const float* __restrict__ ib1s,
                                              const float* __restrict__ nsh,
                                              float* __restrict__ out) {
  int br = blockIdx.x, f = blockIdx.y;
  int b = br / R_;
  int tf = 2 + 2 * f;   // teacher frames 2,4,6
  int sf = 1 + f;       // student frames 1,2,3
  __shared__ __align__(16) float Lsim[4][1024];
  __shared__ __align__(16) float Lrt[1024];
  __shared__ __align__(16) float Lrs[1024];
  __shared__ int sperm[128];
  __shared__ float Lns[2][128];
  __shared__ float scal[22];
  __shared__ float wred[4];
  int t = threadIdx.x;
  {
    const float* rt = reft + (size_t)br * D_;
    const float* rs = refs + (size_t)br * D_;
    *(float4*)&Lrt[t * 4] = *(const float4*)(rt + t * 4);
    *(float4*)&Lrs[t * 4] = *(const float4*)(rs + t * 4);
    #pragma unroll
    for (int k = 0; k < 4; ++k) {
      int m = idx[br * 4 + k]; int j = m / P_, p = m % P_;
      const float* sim = teacher + (((size_t)b * ST_ + 1 + 2 * j) * P_ + p) * D_;
      *(float4*)&Lsim[k][t * 4] = *(const float4*)(sim + t * 4);
    }
  }
  if (t < 128) {
    sperm[t] = shared_perm[t];
    int o = (b * 3 + f) * NS_ + t;
    Lns[0][t] = nsh[o];
    Lns[1][t] = nsh[B_ * 3 * NS_ + o];
  }
  if (t < 4) {
    int o = br * 4 + t;
    scal[t] = prst[o]; scal[4 + t] = prss[o]; scal[8 + t] = pss[o];
    scal[12 + t] = ib1t[o]; scal[16 + t] = ib1s[o];
  }
  if (t == 4) scal[20] = prrt[br];
  if (t == 5) scal[21] = prrs[br];
  __syncthreads();

  const int g = t >> 2, gl = t & 3;
  const int s0 = g, s1 = g + 64;
  const int p0 = sperm[s0], p1 = sperm[s1];
  const float* sht0 = teacher + (((size_t)b * ST_ + tf) * P_ + p0) * D_;
  const float* sht1 = teacher + (((size_t)b * ST_ + tf) * P_ + p1) * D_;
  const float* shs0 = student + (((size_t)b * SS_ + sf) * P_ + p0) * D_;
  const float* shs1 = student + (((size_t)b * SS_ + sf) * P_ + p1) * D_;

  float qtA0 = 0, qtA1 = 0, qtA2 = 0, qtA3 = 0, qtrA = 0;
  float qsA0 = 0, qsA1 = 0, qsA2 = 0, qsA3 = 0, qsrA = 0;
  float qtB0 = 0, qtB1 = 0, qtB2 = 0, qtB3 = 0, qtrB = 0;
  float qsB0 = 0, qsB1 = 0, qsB2 = 0, qsB3 = 0, qsrB = 0;
  #pragma unroll 2
  for (int i = 0; i < 64; ++i) {
    int off = i * 16 + gl * 4;
    float4 a0 = *(const float4*)(sht0 + off);
    float4 a1 = *(const float4*)(sht1 + off);
    float4 c0 = *(const float4*)(shs0 + off);
    float4 c1 = *(const float4*)(shs1 + off);
    float4 v0 = *(const float4*)&Lsim[0][off];
    float4 v1 = *(const float4*)&Lsim[1][off];
    float4 v2 = *(const float4*)&Lsim[2][off];
    float4 v3 = *(const float4*)&Lsim[3][off];
    float4 r1 = *(const float4*)&Lrt[off];
    float4 r2 = *(const float4*)&Lrs[off];
    qtA0 += dot4(a0, v0); qtA1 += dot4(a0, v1); qtA2 += dot4(a0, v2); qtA3 += dot4(a0, v3);
    qtrA += dot4(a0, r1);
    qsA0 += dot4(c0, v0); qsA1 += dot4(c0, v1); qsA2 += dot4(c0, v2); qsA3 += dot4(c0, v3);
    qsrA += dot4(c0, r2);
    qtB0 += dot4(a1, v0); qtB1 += dot4(a1, v1); qtB2 += dot4(a1, v2); qtB3 += dot4(a1, v3);
    qtrB += dot4(a1, r1);
    qsB0 += dot4(c1, v0); qsB1 += dot4(c1, v1); qsB2 += dot4(c1, v2); qsB3 += dot4(c1, v3);
    qsrB += dot4(c1, r2);
  }
  // 2-level butterfly within the 4-lane group
  #pragma unroll
  for (int o = 1; o <= 2; o <<= 1) {
    qtA0 += __shfl_xor(qtA0, o); qtA1 += __shfl_xor(qtA1, o);
    qtA2 += __shfl_xor(qtA2, o); qtA3 += __shfl_xor(qtA3, o);
    qtrA += __shfl_xor(qtrA, o);
    qsA0 += __shfl_xor(qsA0, o); qsA1 += __shfl_xor(qsA1, o);
    qsA2 += __shfl_xor(qsA2, o); qsA3 += __shfl_xor(qsA3, o);
    qsrA += __shfl_xor(qsrA, o);
    qtB0 += __shfl_xor(qtB0, o); qtB1 += __shfl_xor(qtB1, o);
    qtB2 += __shfl_xor(qtB2, o); qtB3 += __shfl_xor(qtB3, o);
    qtrB += __shfl_xor(qtrB, o);
    qsB0 += __shfl_xor(qsB0, o); qsB1 += __shfl_xor(qsB1, o);
    qsB2 += __shfl_xor(qsB2, o); qsB3 += __shfl_xor(qsB3, o);
    qsrB += __shfl_xor(qsrB, o);
  }
  // lane gl handles k = gl for both s rows (static selects, no scratch)
  const int k = gl;
  const float Prs_t = scal[k], Prs_s = scal[4 + k], Pss_k = scal[8 + k];
  const float ibt = scal[12 + k], ibs = scal[16 + k];
  const float Prr_t = scal[20], Prr_s = scal[21];

  auto epi = [&](float qsim, float qsimS, float qref, float qrefS,
                 float qss, float qssS) -> float {
    float n1sq = qss - 2.f * qref + Prr_t;
    float i1 = 1.f / fmaxf(sqrtf(fmaxf(n1sq, 0.f)), 1e-8f);
    float n2sq = qss - 2.f * qsim + Pss_k;
    float i2 = 1.f / fmaxf(sqrtf(fmaxf(n2sq, 0.f)), 1e-8f);
    float a1t = (qsim - qref - Prs_t + Prr_t) * ibt * i1;
    float a2t = -(qsim - Pss_k - qref + Prs_t) * ibt * i2;
    float a3t = (qss - qsim - qref + Prs_t) * i1 * i2;
    float n1sqS = qssS - 2.f * qrefS + Prr_s;
    float i1s = 1.f / fmaxf(sqrtf(fmaxf(n1sqS, 0.f)), 1e-8f);
    float n2sqS = qssS - 2.f * qsimS + Pss_k;
    float i2s = 1.f / fmaxf(sqrtf(fmaxf(n2sqS, 0.f)), 1e-8f);
    float a1s = (qsimS - qrefS - Prs_s + Prr_s) * ibs * i1s;
    float a2s = -(qsimS - Pss_k - qrefS + Prs_s) * ibs * i2s;
    float a3s = (qssS - qsimS - qrefS + Prs_s) * i1s * i2s;
    return huber1(a1s - a1t) + huber1(a2s - a2t) + huber1(a3s - a3t);
  };

  float qsimA  = (gl == 0) ? qtA0 : (gl == 1) ? qtA1 : (gl == 2) ? qtA2 : qtA3;
  float qsimSA = (gl == 0) ? qsA0 : (gl == 1) ? qsA1 : (gl == 2) ? qsA2 : qsA3;
  float qsimB  = (gl == 0) ? qtB0 : (gl == 1) ? qtB1 : (gl == 2) ? qtB2 : qtB3;
  float qsimSB = (gl == 0) ? qsB0 : (gl == 1) ? qsB1 : (gl == 2) ? qsB2 : qsB3;

  float lacc = epi(qsimA, qsimSA, qtrA, qsrA, Lns[0][s0], Lns[1][s0])
             + epi(qsimB, qsimSB, qtrB, qsrB, Lns[0][s1], Lns[1][s1]);

  // block reduction
  int w = t >> 6, lane = t & 63;
  for (int o = 32; o; o >>= 1) lacc += __shfl_down(lacc, o);
  if (lane == 0) wred[w] = lacc;
  __syncthreads();
  if (t == 0) {
    float ssum = wred[0] + wred[1] + wred[2] + wred[3];
    atomicAdd(out, ssum * (1.0f / 393216.0f));  // /= B*R*NS*K*3 (W1=W2=W3=1)
  }
}

// ---------------------------------------------------------------------------
extern "C" void kernel_launch(void* const* d_in, const int* in_sizes, int n_in,
                              void* d_out, int out_size, void* d_ws, size_t ws_size,
                              hipStream_t stream) {
  const float* teacher = (const float*)d_in[0];
  const float* student = (const float*)d_in[1];
  const int* ref_perm = (const int*)d_in[2];
  const int* shared_perm = (const int*)d_in[3];
  float* ws = (float*)d_ws;
  float* invn = ws + OFF_INVN;
  float* reft = ws + OFF_REFT;
  float* refs = ws + OFF_REFS;
  float* prrt = ws + OFF_PRRT;
  float* prrs = ws + OFF_PRRS;
  int*   idx  = (int*)(ws + OFF_IDX);
  float* prst = ws + OFF_PRST;
  float* prss = ws + OFF_PRSS;
  float* pss  = ws + OFF_PSS;
  float* ib1t = ws + OFF_IB1T;
  float* ib1s = ws + OFF_IB1S;
  float* nsh  = ws + OFF_NSH;
  float* candv = ws + OFF_CANDV;
  int*   candi = (int*)(ws + OFF_CANDI);
  float* Cp   = ws + OFF_C;

  hipMemsetAsync(d_out, 0, sizeof(float), stream);

  k_prep0<<<NA_BLOCKS + NB_BLOCKS + NC_BLOCKS, 256, 0, stream>>>(
      teacher, student, ref_perm, shared_perm, invn, nsh, reft, refs, prrt, prrs);
  k_sim_gemm<<<1376, 256, 0, stream>>>(teacher, reft, Cp);
  k_topk1<<<1024, 256, 0, stream>>>(Cp, invn, candv, candi);
  k_prep<<<B_ * R_, 256, 0, stream>>>(teacher, reft, refs, candv, candi, idx,
                                      prst, prss, pss, ib1t, ib1s);
  k_loss<<<dim3(B_ * R_, 3), 256, 0, stream>>>(teacher, student, shared_perm, idx,
                                               reft, refs, prrt, prrs,
                                               prst, prss, pss, ib1t, ib1s,
                                               nsh, (float*)d_out);
}

// Round 13
// 294.387 us; speedup vs baseline: 1.7963x; 1.0373x over previous
//
#include <hip/hip_runtime.h>
#include <float.h>

// Problem constants
#define B_  2
#define ST_ 8      // teacher frames
#define SS_ 4      // student frames
#define P_  1369
#define D_  1024
#define R_  128
#define NS_ 128
#define K_  4
#define M_  5476   // 4 * P_ (extra frames 1,3,5,7 flattened)
#define BM_ 10952u // B_*M_

// Workspace layout (float offsets). Total ~11.85M floats (~47.4 MB; ws is ~350 MB).
#define OFF_REFT  0u
#define OFF_REFS  (OFF_REFT + 262144u)
#define OFF_PRRT  (OFF_REFS + 262144u)
#define OFF_PRRS  (OFF_PRRT + 256u)
#define OFF_IDX   (OFF_PRRS + 256u)
#define OFF_PRST  (OFF_IDX + 1024u)
#define OFF_PRSS  (OFF_PRST + 1024u)
#define OFF_PSS   (OFF_PRSS + 1024u)
#define OFF_IB1T  (OFF_PSS + 1024u)
#define OFF_IB1S  (OFF_IB1T + 1024u)
#define OFF_NSH   (OFF_IB1S + 1024u)   // 1536 floats
#define OFF_CANDV (OFF_NSH + 1536u)    // 256 br x 16 candidate values
#define OFF_CANDI (OFF_CANDV + 4096u)  // 256 br x 16 candidate indices
#define OFF_NSQ   (OFF_CANDI + 4096u)  // 8 x B_ x M_ partial row sumsq = 87616
#define OFF_C     (OFF_NSQ + 87616u)   // 8 partial buffers, each CP_ floats
#define CP_       1401856u             // B_*R_*M_

// fused-prep block ranges (extra_norms now fused into k_sim_gemm)
#define NB_BLOCKS 384    // 1536/4  shnorm rows
#define NC_BLOCKS 256    // B_*R_   ref_gather

__device__ __forceinline__ float dot4(const float4 a, const float4 b) {
  return a.x*b.x + a.y*b.y + a.z*b.z + a.w*b.w;
}

// ---------------------------------------------------------------------------
// K0: fused prep = shared-row norms + ref gather.
__global__ __launch_bounds__(256) void k_prep0(const float* __restrict__ teacher,
                                               const float* __restrict__ student,
                                               const int* __restrict__ ref_perm,
                                               const int* __restrict__ shared_perm,
                                               float* __restrict__ nsh,
                                               float* __restrict__ reft,
                                               float* __restrict__ refs,
                                               float* __restrict__ prrt,
                                               float* __restrict__ prrs) {
  const int bid = blockIdx.x;
  const int t = threadIdx.x;
  if (bid < NB_BLOCKS) {
    // shared-row squared norms, one wave per row
    int row = bid * 4 + (t >> 6);
    int lane = t & 63;
    if (row >= 2 * B_ * 3 * NS_) return;
    int rid = row % (B_ * 3 * NS_);
    int is_stu = row / (B_ * 3 * NS_);
    int b = rid / (3 * NS_);
    int rem = rid % (3 * NS_);
    int f = rem / NS_, s = rem % NS_;
    int p = shared_perm[s];
    const float* src = is_stu
        ? student + (((size_t)b * SS_ + 1 + f) * P_ + p) * D_
        : teacher + (((size_t)b * ST_ + 2 + 2 * f) * P_ + p) * D_;
    float acc = 0.f;
    #pragma unroll
    for (int it = 0; it < 4; ++it) {
      float4 v = *(const float4*)(src + (it * 64 + lane) * 4);
      acc += dot4(v, v);
    }
    for (int o = 32; o; o >>= 1) acc += __shfl_down(acc, o);
    if (lane == 0) nsh[row] = acc;
  } else {
    // ref gather + squared norms, one block per br
    int br = bid - NB_BLOCKS;
    int b = br / R_, r = br % R_;
    int p = ref_perm[r];
    const float* st = teacher + (((size_t)b * ST_ + 0) * P_ + p) * D_;
    const float* ss = student + (((size_t)b * SS_ + 0) * P_ + p) * D_;
    float* dt = reft + (size_t)br * D_;
    float* dsp = refs + (size_t)br * D_;
    float4 vt = *(const float4*)(st + t * 4);
    float4 vs = *(const float4*)(ss + t * 4);
    *(float4*)(dt + t * 4) = vt;
    *(float4*)(dsp + t * 4) = vs;
    float at = dot4(vt, vt);
    float as = dot4(vs, vs);
    for (int o = 32; o; o >>= 1) { at += __shfl_down(at, o); as += __shfl_down(as, o); }
    __shared__ float red[16];
    int w = t >> 6, lane = t & 63;
    if (lane == 0) { red[w] = at; red[8 + w] = as; }
    __syncthreads();
    if (t == 0) {
      prrt[br] = red[0] + red[1] + red[2] + red[3];
      prrs[br] = red[8] + red[9] + red[10] + red[11];
    }
  }
}

// ---------------------------------------------------------------------------
// K2 v4: split-K x8 (2752 blocks ~ 8-9/CU) into 8 SEPARATE partial buffers,
// plain stores. FUSED: rt==0 blocks also compute E-row partial sum-of-squares
// during staging (8 FMA + 6 shfl per chunk) -> nsq[kq][b][m]; the separate
// extra_norms pass (45 MB re-read) is eliminated.
__global__ __launch_bounds__(256) void k_sim_gemm(const float* __restrict__ teacher,
                                                  const float* __restrict__ reft,
                                                  float* __restrict__ Cp,
                                                  float* __restrict__ nsq) {
  const int bid = blockIdx.x;            // 2(b) * 2(rt) * 86(mt) * 8(kq) = 2752
  const int kq  = bid & 7;
  const int rest = bid >> 3;
  const int b   = rest / 172;
  const int rem = rest % 172;
  const int rtb = rem / 86;
  const int mt  = rem % 86;
  const int r0 = rtb * 64, m0 = mt * 64;
  __shared__ __align__(16) float Al[32 * 68];
  __shared__ __align__(16) float El[32 * 68];
  const int t = threadIdx.x;
  const int tx = t & 15, ty = t >> 4;
  const int lr = t >> 3;
  const int lk = (t & 7) * 4;
  const float* arow0 = reft + (size_t)(b * R_ + r0 + lr) * D_;
  const float* arow1 = reft + (size_t)(b * R_ + r0 + 32 + lr) * D_;
  const float* erow0; const float* erow1; bool ev0, ev1;
  {
    int m = m0 + lr; ev0 = m < M_;
    int mm = ev0 ? m : 0; int j = mm / P_, p = mm % P_;
    erow0 = teacher + (((size_t)b * ST_ + 1 + 2 * j) * P_ + p) * D_;
    m = m0 + 32 + lr; ev1 = m < M_;
    mm = ev1 ? m : 0; j = mm / P_; p = mm % P_;
    erow1 = teacher + (((size_t)b * ST_ + 1 + 2 * j) * P_ + p) * D_;
  }
  float acc[4][4];
  #pragma unroll
  for (int i = 0; i < 4; ++i)
    #pragma unroll
    for (int j = 0; j < 4; ++j) acc[i][j] = 0.f;
  float nsq0 = 0.f, nsq1 = 0.f;

  const int kbeg = kq * 128, kend = kbeg + 128;
  for (int kc = kbeg; kc < kend; kc += 32) {
    __syncthreads();
    float4 a0 = *(const float4*)(arow0 + kc + lk);
    float4 a1 = *(const float4*)(arow1 + kc + lk);
    float4 e0 = ev0 ? *(const float4*)(erow0 + kc + lk) : make_float4(0, 0, 0, 0);
    float4 e1 = ev1 ? *(const float4*)(erow1 + kc + lk) : make_float4(0, 0, 0, 0);
    if (rtb == 0) {
      // partial row sumsq: reduce over the 8 staging lanes of each row
      float d0 = dot4(e0, e0), d1 = dot4(e1, e1);
      #pragma unroll
      for (int o = 1; o <= 4; o <<= 1) {
        d0 += __shfl_xor(d0, o);
        d1 += __shfl_xor(d1, o);
      }
      nsq0 += d0; nsq1 += d1;
    }
    Al[(lk + 0) * 68 + lr] = a0.x; Al[(lk + 1) * 68 + lr] = a0.y;
    Al[(lk + 2) * 68 + lr] = a0.z; Al[(lk + 3) * 68 + lr] = a0.w;
    Al[(lk + 0) * 68 + 32 + lr] = a1.x; Al[(lk + 1) * 68 + 32 + lr] = a1.y;
    Al[(lk + 2) * 68 + 32 + lr] = a1.z; Al[(lk + 3) * 68 + 32 + lr] = a1.w;
    El[(lk + 0) * 68 + lr] = e0.x; El[(lk + 1) * 68 + lr] = e0.y;
    El[(lk + 2) * 68 + lr] = e0.z; El[(lk + 3) * 68 + lr] = e0.w;
    El[(lk + 0) * 68 + 32 + lr] = e1.x; El[(lk + 1) * 68 + 32 + lr] = e1.y;
    El[(lk + 2) * 68 + 32 + lr] = e1.z; El[(lk + 3) * 68 + 32 + lr] = e1.w;
    __syncthreads();
    #pragma unroll
    for (int kk = 0; kk < 32; ++kk) {
      float4 av = *(const float4*)&Al[kk * 68 + ty * 4];
      float4 ev = *(const float4*)&El[kk * 68 + tx * 4];
      acc[0][0] += av.x * ev.x; acc[0][1] += av.x * ev.y; acc[0][2] += av.x * ev.z; acc[0][3] += av.x * ev.w;
      acc[1][0] += av.y * ev.x; acc[1][1] += av.y * ev.y; acc[1][2] += av.y * ev.z; acc[1][3] += av.y * ev.w;
      acc[2][0] += av.z * ev.x; acc[2][1] += av.z * ev.y; acc[2][2] += av.z * ev.z; acc[2][3] += av.z * ev.w;
      acc[3][0] += av.w * ev.x; acc[3][1] += av.w * ev.y; acc[3][2] += av.w * ev.z; acc[3][3] += av.w * ev.w;
    }
  }
  if (rtb == 0 && (t & 7) == 0) {
    float* nq = nsq + (size_t)kq * BM_ + (size_t)b * M_;
    int mA = m0 + lr;
    if (mA < M_) nq[mA] = nsq0;
    int mB = m0 + 32 + lr;
    if (mB < M_) nq[mB] = nsq1;
  }
  const int mbase = m0 + tx * 4;
  float* cbase = Cp + (size_t)kq * CP_;
  #pragma unroll
  for (int i = 0; i < 4; ++i) {
    int r = r0 + ty * 4 + i;
    float* crow = cbase + (size_t)(b * R_ + r) * M_;
    if (mbase + 3 < M_) {
      *(float4*)(crow + mbase) = make_float4(acc[i][0], acc[i][1], acc[i][2], acc[i][3]);
    } else {
      if (mbase + 0 < M_) crow[mbase + 0] = acc[i][0];
      if (mbase + 1 < M_) crow[mbase + 1] = acc[i][1];
      if (mbase + 2 < M_) crow[mbase + 2] = acc[i][2];
      if (mbase + 3 < M_) crow[mbase + 3] = acc[i][3];
    }
  }
}

// ---------------------------------------------------------------------------
// Top-k helpers: (value desc, index asc) total order = lax.top_k rule.
__device__ __forceinline__ void topk_insert(float v, int m, float bv[4], int bi[4]) {
  bool better3 = (v > bv[3]) || (v == bv[3] && m < bi[3]);
  if (!better3) return;
  int pos = 3;
  while (pos > 0) {
    bool better = (v > bv[pos - 1]) || (v == bv[pos - 1] && m < bi[pos - 1]);
    if (better) { bv[pos] = bv[pos - 1]; bi[pos] = bi[pos - 1]; --pos; }
    else break;
  }
  bv[pos] = v; bi[pos] = m;
}

// K3a: stage-1 top-4 per (br, chunk of M/4). 1024 blocks. Sums the 8 split-K
// partials + 8 norm partials in fixed order (deterministic), applies
// 1/max(sqrt(nsq),1e-12) (positive scale), selects.
__global__ __launch_bounds__(256) void k_topk1(const float* __restrict__ Cp,
                                               const float* __restrict__ nsq,
                                               float* __restrict__ candv,
                                               int* __restrict__ candi) {
  int bid = blockIdx.x;            // br*4 + q
  int br = bid >> 2, q = bid & 3;
  int b = br / R_;
  const float* crow = Cp + (size_t)br * M_;
  const float* nrow = nsq + (size_t)b * M_;
  const int mbeg = q * 1369, mend = mbeg + 1369;
  int t = threadIdx.x;
  float bv[4] = {-FLT_MAX, -FLT_MAX, -FLT_MAX, -FLT_MAX};
  int   bi[4] = {0x7fffffff, 0x7fffffff, 0x7fffffff, 0x7fffffff};
  for (int m = mbeg + t; m < mend; m += 256) {
    float v = 0.f, n = 0.f;
    #pragma unroll
    for (int q8 = 0; q8 < 8; ++q8) {
      v += crow[(size_t)q8 * CP_ + m];
      n += nrow[(size_t)q8 * BM_ + m];
    }
    float inv = 1.f / fmaxf(sqrtf(n), 1e-12f);
    topk_insert(v * inv, m, bv, bi);
  }
  #pragma unroll
  for (int o = 1; o < 64; o <<= 1) {
    float ov[4]; int oi[4];
    #pragma unroll
    for (int qq = 0; qq < 4; ++qq) {
      ov[qq] = __shfl_xor(bv[qq], o);
      oi[qq] = __shfl_xor(bi[qq], o);
    }
    #pragma unroll
    for (int qq = 0; qq < 4; ++qq) topk_insert(ov[qq], oi[qq], bv, bi);
  }
  __shared__ float sv[16];
  __shared__ int   si[16];
  int wv = t >> 6, lane = t & 63;
  if (lane == 0) {
    #pragma unroll
    for (int qq = 0; qq < 4; ++qq) { sv[wv * 4 + qq] = bv[qq]; si[wv * 4 + qq] = bi[qq]; }
  }
  __syncthreads();
  if (t == 0) {
    float tv[4] = {-FLT_MAX, -FLT_MAX, -FLT_MAX, -FLT_MAX};
    int   ti[4] = {0x7fffffff, 0x7fffffff, 0x7fffffff, 0x7fffffff};
    #pragma unroll
    for (int e = 0; e < 16; ++e) topk_insert(sv[e], si[e], tv, ti);
    #pragma unroll
    for (int qq = 0; qq < 4; ++qq) { candv[bid * 4 + qq] = tv[qq]; candi[bid * 4 + qq] = ti[qq]; }
  }
}

// ---------------------------------------------------------------------------
// K4: stage-2 merge (wave 0, shfl butterfly over 16 candidates) + per (br,k)
// scalars: ||sim||^2, ref_t.sim, ref_s.sim, 1/max(||sim-ref_x||,eps).
__global__ __launch_bounds__(256) void k_prep(const float* __restrict__ teacher,
                                              const float* __restrict__ reft,
                                              const float* __restrict__ refs,
                                              const float* __restrict__ candv,
                                              const int* __restrict__ candi,
                                              int* __restrict__ idxout,
                                              float* __restrict__ prst,
                                              float* __restrict__ prss,
                                              float* __restrict__ pss,
                                              float* __restrict__ ib1t,
                                              float* __restrict__ ib1s) {
  int br = blockIdx.x;
  int b = br / R_;
  int t = threadIdx.x;
  __shared__ int sidx[4];
  if (t < 64) {
    float v = -FLT_MAX; int ix = 0x7fffffff;
    if (t < 16) { v = candv[br * 16 + t]; ix = candi[br * 16 + t]; }
    float bv[4] = {v, -FLT_MAX, -FLT_MAX, -FLT_MAX};
    int   bi[4] = {ix, 0x7fffffff, 0x7fffffff, 0x7fffffff};
    #pragma unroll
    for (int o = 1; o <= 8; o <<= 1) {
      float ov[4]; int oi[4];
      #pragma unroll
      for (int q = 0; q < 4; ++q) {
        ov[q] = __shfl_xor(bv[q], o);
        oi[q] = __shfl_xor(bi[q], o);
      }
      #pragma unroll
      for (int q = 0; q < 4; ++q) topk_insert(ov[q], oi[q], bv, bi);
    }
    if (t == 0) {
      #pragma unroll
      for (int q = 0; q < 4; ++q) { sidx[q] = bi[q]; idxout[br * 4 + q] = bi[q]; }
    }
  }
  __syncthreads();
  int w = t >> 6, lane = t & 63;
  int m = sidx[w];
  int j = m / P_, p = m % P_;
  const float* sim = teacher + (((size_t)b * ST_ + 1 + 2 * j) * P_ + p) * D_;
  const float* rt = reft + (size_t)br * D_;
  const float* rs = refs + (size_t)br * D_;
  float s_ss = 0, s_rt = 0, s_rs = 0, s_dt = 0, s_ds = 0;
  #pragma unroll
  for (int it = 0; it < 4; ++it) {
    int d = (it * 64 + lane) * 4;
    float4 svv = *(const float4*)(sim + d);
    float4 tvv = *(const float4*)(rt + d);
    float4 uvv = *(const float4*)(rs + d);
    s_ss += dot4(svv, svv);
    s_rt += dot4(svv, tvv);
    s_rs += dot4(svv, uvv);
    float4 dt = make_float4(svv.x - tvv.x, svv.y - tvv.y, svv.z - tvv.z, svv.w - tvv.w);
    float4 ds = make_float4(svv.x - uvv.x, svv.y - uvv.y, svv.z - uvv.z, svv.w - uvv.w);
    s_dt += dot4(dt, dt);
    s_ds += dot4(ds, ds);
  }
  for (int o = 32; o; o >>= 1) {
    s_ss += __shfl_down(s_ss, o); s_rt += __shfl_down(s_rt, o); s_rs += __shfl_down(s_rs, o);
    s_dt += __shfl_down(s_dt, o); s_ds += __shfl_down(s_ds, o);
  }
  if (lane == 0) {
    int o = br * 4 + w;
    pss[o] = s_ss; prst[o] = s_rt; prss[o] = s_rs;
    ib1t[o] = 1.f / fmaxf(sqrtf(s_dt), 1e-8f);
    ib1s[o] = 1.f / fmaxf(sqrtf(s_ds), 1e-8f);
  }
}

// ---------------------------------------------------------------------------
// K5 v3: fused loss. Block = (br, frame); 64 groups of 4 lanes, each group
// owns TWO s rows -> 6 LDS reads feed 20 dot4s (LDS off critical path).
__device__ __forceinline__ float huber1(float d) {
  float ad = fabsf(d);
  return (ad < 1.0f) ? 0.5f * d * d : (ad - 0.5f);
}

__global__ __launch_bounds__(256) void k_loss(const float* __restrict__ teacher,
                                              const float* __restrict__ student,
                                              const int* __restrict__ shared_perm,
                                              const int* __restrict__ idx,
                                              const float* __restrict__ reft,
                                              const float* __restrict__ refs,
                                              const float* __restrict__ prrt,
                                              const float* __restrict__ prrs,
                                              const float* __restrict__ prst,
                                              const float* __restrict__ prss,
                                              const float* __restrict__ pss,
                                              const float* __restrict__ ib1t,
                                              const float* __restrict__ ib1s,
                                              const float* __restrict__ nsh,
                                              float* __restrict__ out) {
  int br = blockIdx.x, f = blockIdx.y;
  int b = br / R_;
  int tf = 2 + 2 * f;   // teacher frames 2,4,6
  int sf = 1 + f;       // student frames 1,2,3
  __shared__ __align__(16) float Lsim[4][1024];
  __shared__ __align__(16) float Lrt[1024];
  __shared__ __align__(16) float Lrs[1024];
  __shared__ int sperm[128];
  __shared__ float Lns[2][128];
  __shared__ float scal[22];
  __shared__ float wred[4];
  int t = threadIdx.x;
  {
    const float* rt = reft + (size_t)br * D_;
    const float* rs = refs + (size_t)br * D_;
    *(float4*)&Lrt[t * 4] = *(const float4*)(rt + t * 4);
    *(float4*)&Lrs[t * 4] = *(const float4*)(rs + t * 4);
    #pragma unroll
    for (int k = 0; k < 4; ++k) {
      int m = idx[br * 4 + k]; int j = m / P_, p = m % P_;
      const float* sim = teacher + (((size_t)b * ST_ + 1 + 2 * j) * P_ + p) * D_;
      *(float4*)&Lsim[k][t * 4] = *(const float4*)(sim + t * 4);
    }
  }
  if (t < 128) {
    sperm[t] = shared_perm[t];
    int o = (b * 3 + f) * NS_ + t;
    Lns[0][t] = nsh[o];
    Lns[1][t] = nsh[B_ * 3 * NS_ + o];
  }
  if (t < 4) {
    int o = br * 4 + t;
    scal[t] = prst[o]; scal[4 + t] = prss[o]; scal[8 + t] = pss[o];
    scal[12 + t] = ib1t[o]; scal[16 + t] = ib1s[o];
  }
  if (t == 4) scal[20] = prrt[br];
  if (t == 5) scal[21] = prrs[br];
  __syncthreads();

  const int g = t >> 2, gl = t & 3;
  const int s0 = g, s1 = g + 64;
  const int p0 = sperm[s0], p1 = sperm[s1];
  const float* sht0 = teacher + (((size_t)b * ST_ + tf) * P_ + p0) * D_;
  const float* sht1 = teacher + (((size_t)b * ST_ + tf) * P_ + p1) * D_;
  const float* shs0 = student + (((size_t)b * SS_ + sf) * P_ + p0) * D_;
  const float* shs1 = student + (((size_t)b * SS_ + sf) * P_ + p1) * D_;

  float qtA0 = 0, qtA1 = 0, qtA2 = 0, qtA3 = 0, qtrA = 0;
  float qsA0 = 0, qsA1 = 0, qsA2 = 0, qsA3 = 0, qsrA = 0;
  float qtB0 = 0, qtB1 = 0, qtB2 = 0, qtB3 = 0, qtrB = 0;
  float qsB0 = 0, qsB1 = 0, qsB2 = 0, qsB3 = 0, qsrB = 0;
  #pragma unroll 2
  for (int i = 0; i < 64; ++i) {
    int off = i * 16 + gl * 4;
    float4 a0 = *(const float4*)(sht0 + off);
    float4 a1 = *(const float4*)(sht1 + off);
    float4 c0 = *(const float4*)(shs0 + off);
    float4 c1 = *(const float4*)(shs1 + off);
    float4 v0 = *(const float4*)&Lsim[0][off];
    float4 v1 = *(const float4*)&Lsim[1][off];
    float4 v2 = *(const float4*)&Lsim[2][off];
    float4 v3 = *(const float4*)&Lsim[3][off];
    float4 r1 = *(const float4*)&Lrt[off];
    float4 r2 = *(const float4*)&Lrs[off];
    qtA0 += dot4(a0, v0); qtA1 += dot4(a0, v1); qtA2 += dot4(a0, v2); qtA3 += dot4(a0, v3);
    qtrA += dot4(a0, r1);
    qsA0 += dot4(c0, v0); qsA1 += dot4(c0, v1); qsA2 += dot4(c0, v2); qsA3 += dot4(c0, v3);
    qsrA += dot4(c0, r2);
    qtB0 += dot4(a1, v0); qtB1 += dot4(a1, v1); qtB2 += dot4(a1, v2); qtB3 += dot4(a1, v3);
    qtrB += dot4(a1, r1);
    qsB0 += dot4(c1, v0); qsB1 += dot4(c1, v1); qsB2 += dot4(c1, v2); qsB3 += dot4(c1, v3);
    qsrB += dot4(c1, r2);
  }
  // 2-level butterfly within the 4-lane group
  #pragma unroll
  for (int o = 1; o <= 2; o <<= 1) {
    qtA0 += __shfl_xor(qtA0, o); qtA1 += __shfl_xor(qtA1, o);
    qtA2 += __shfl_xor(qtA2, o); qtA3 += __shfl_xor(qtA3, o);
    qtrA += __shfl_xor(qtrA, o);
    qsA0 += __shfl_xor(qsA0, o); qsA1 += __shfl_xor(qsA1, o);
    qsA2 += __shfl_xor(qsA2, o); qsA3 += __shfl_xor(qsA3, o);
    qsrA += __shfl_xor(qsrA, o);
    qtB0 += __shfl_xor(qtB0, o); qtB1 += __shfl_xor(qtB1, o);
    qtB2 += __shfl_xor(qtB2, o); qtB3 += __shfl_xor(qtB3, o);
    qtrB += __shfl_xor(qtrB, o);
    qsB0 += __shfl_xor(qsB0, o); qsB1 += __shfl_xor(qsB1, o);
    qsB2 += __shfl_xor(qsB2, o); qsB3 += __shfl_xor(qsB3, o);
    qsrB += __shfl_xor(qsrB, o);
  }
  const int k = gl;
  const float Prs_t = scal[k], Prs_s = scal[4 + k], Pss_k = scal[8 + k];
  const float ibt = scal[12 + k], ibs = scal[16 + k];
  const float Prr_t = scal[20], Prr_s = scal[21];

  auto epi = [&](float qsim, float qsimS, float qref, float qrefS,
                 float qss, float qssS) -> float {
    float n1sq = qss - 2.f * qref + Prr_t;
    float i1 = 1.f / fmaxf(sqrtf(fmaxf(n1sq, 0.f)), 1e-8f);
    float n2sq = qss - 2.f * qsim + Pss_k;
    float i2 = 1.f / fmaxf(sqrtf(fmaxf(n2sq, 0.f)), 1e-8f);
    float a1t = (qsim - qref - Prs_t + Prr_t) * ibt * i1;
    float a2t = -(qsim - Pss_k - qref + Prs_t) * ibt * i2;
    float a3t = (qss - qsim - qref + Prs_t) * i1 * i2;
    float n1sqS = qssS - 2.f * qrefS + Prr_s;
    float i1s = 1.f / fmaxf(sqrtf(fmaxf(n1sqS, 0.f)), 1e-8f);
    float n2sqS = qssS - 2.f * qsimS + Pss_k;
    float i2s = 1.f / fmaxf(sqrtf(fmaxf(n2sqS, 0.f)), 1e-8f);
    float a1s = (qsimS - qrefS - Prs_s + Prr_s) * ibs * i1s;
    float a2s = -(qsimS - Pss_k - qrefS + Prs_s) * ibs * i2s;
    float a3s = (qssS - qsimS - qrefS + Prs_s) * i1s * i2s;
    return huber1(a1s - a1t) + huber1(a2s - a2t) + huber1(a3s - a3t);
  };

  float qsimA  = (gl == 0) ? qtA0 : (gl == 1) ? qtA1 : (gl == 2) ? qtA2 : qtA3;
  float qsimSA = (gl == 0) ? qsA0 : (gl == 1) ? qsA1 : (gl == 2) ? qsA2 : qsA3;
  float qsimB  = (gl == 0) ? qtB0 : (gl == 1) ? qtB1 : (gl == 2) ? qtB2 : qtB3;
  float qsimSB = (gl == 0) ? qsB0 : (gl == 1) ? qsB1 : (gl == 2) ? qsB2 : qsB3;

  float lacc = epi(qsimA, qsimSA, qtrA, qsrA, Lns[0][s0], Lns[1][s0])
             + epi(qsimB, qsimSB, qtrB, qsrB, Lns[0][s1], Lns[1][s1]);

  // block reduction
  int w = t >> 6, lane = t & 63;
  for (int o = 32; o; o >>= 1) lacc += __shfl_down(lacc, o);
  if (lane == 0) wred[w] = lacc;
  __syncthreads();
  if (t == 0) {
    float ssum = wred[0] + wred[1] + wred[2] + wred[3];
    atomicAdd(out, ssum * (1.0f / 393216.0f));  // /= B*R*NS*K*3 (W1=W2=W3=1)
  }
}

// ---------------------------------------------------------------------------
extern "C" void kernel_launch(void* const* d_in, const int* in_sizes, int n_in,
                              void* d_out, int out_size, void* d_ws, size_t ws_size,
                              hipStream_t stream) {
  const float* teacher = (const float*)d_in[0];
  const float* student = (const float*)d_in[1];
  const int* ref_perm = (const int*)d_in[2];
  const int* shared_perm = (const int*)d_in[3];
  float* ws = (float*)d_ws;
  float* reft = ws + OFF_REFT;
  float* refs = ws + OFF_REFS;
  float* prrt = ws + OFF_PRRT;
  float* prrs = ws + OFF_PRRS;
  int*   idx  = (int*)(ws + OFF_IDX);
  float* prst = ws + OFF_PRST;
  float* prss = ws + OFF_PRSS;
  float* pss  = ws + OFF_PSS;
  float* ib1t = ws + OFF_IB1T;
  float* ib1s = ws + OFF_IB1S;
  float* nsh  = ws + OFF_NSH;
  float* candv = ws + OFF_CANDV;
  int*   candi = (int*)(ws + OFF_CANDI);
  float* nsq  = ws + OFF_NSQ;
  float* Cp   = ws + OFF_C;

  hipMemsetAsync(d_out, 0, sizeof(float), stream);

  k_prep0<<<NB_BLOCKS + NC_BLOCKS, 256, 0, stream>>>(
      teacher, student, ref_perm, shared_perm, nsh, reft, refs, prrt, prrs);
  k_sim_gemm<<<2752, 256, 0, stream>>>(teacher, reft, Cp, nsq);
  k_topk1<<<1024, 256, 0, stream>>>(Cp, nsq, candv, candi);
  k_prep<<<B_ * R_, 256, 0, stream>>>(teacher, reft, refs, candv, candi, idx,
                                      prst, prss, pss, ib1t, ib1s);
  k_loss<<<dim3(B_ * R_, 3), 256, 0, stream>>>(teacher, student, shared_perm, idx,
                                               reft, refs, prrt, prrs,
                                               prst, prss, pss, ib1t, ib1s,
                                               nsh, (float*)d_out);
}